// Round 5
// baseline (417.337 us; speedup 1.0000x reference)
//
#include <hip/hip_runtime.h>

#define BATCH   4096
#define IN_SZ   512
#define NQ      12
#define OUT_SZ  256
#define DEPTH   3
#define NST     4096   // 2^NQ
#define BN_EPS  1e-5f

// ---- ws layout (in floats) ----
#define OFF_ENC    0            // 4096*12 = 49152
#define OFF_BN1M   49152
#define OFF_BN1R   49168
#define OFF_GU     49184        // 288
#define OFF_GC     49472        // 66 (pad 96)
#define OFF_PROBS  49568        // 49152
#define OFF_PMEAN  98720
#define OFF_COV    98736        // 144

// ================= K1: encode (+ fused gate precompute in block 192) =================
__global__ void k_encode(const float* __restrict__ x, const float* __restrict__ w,
                         const float* __restrict__ bvec,
                         const float* __restrict__ rot, const float* __restrict__ ent,
                         float* __restrict__ enc, float* __restrict__ gU, float* __restrict__ gC) {
    if (blockIdx.x == 192) {
        int t = threadIdx.x;
        if (t < DEPTH * NQ) {
            float ax = rot[t * 3 + 0] * 0.5f;
            float ay = rot[t * 3 + 1] * 0.5f;
            float az = rot[t * 3 + 2] * 0.5f;
            float cx = cosf(ax), sx = sinf(ax);
            float cy = cosf(ay), sy = sinf(ay);
            float cz = cosf(az), sz = sinf(az);
            float m00r =  cy * cx, m00i =  sy * sx;
            float m01r = -sy * cx, m01i = -cy * sx;
            float m10r =  sy * cx, m10i = -cy * sx;
            float m11r =  cy * cx, m11i = -sy * sx;
            float* o = gU + t * 8;
            o[0] = cz * m00r + sz * m00i;  o[1] = cz * m00i - sz * m00r;
            o[2] = cz * m01r + sz * m01i;  o[3] = cz * m01i - sz * m01r;
            o[4] = cz * m10r - sz * m10i;  o[5] = cz * m10i + sz * m10r;
            o[6] = cz * m11r - sz * m11i;  o[7] = cz * m11i + sz * m11r;
        }
        if (t >= 64 && t - 64 < DEPTH * (NQ - 1)) {
            int i = t - 64;
            float th = ent[i] * 0.5f;
            gC[i * 2 + 0] = cosf(th);
            gC[i * 2 + 1] = sinf(th);
        }
        return;
    }
    int gi = blockIdx.x * 256 + threadIdx.x;
    int row = gi / NQ;
    int q   = gi - row * NQ;
    const float4* xr = (const float4*)(x + row * IN_SZ);
    const float4* wr = (const float4*)(w + q * IN_SZ);
    float acc = 0.f;
    for (int k = 0; k < IN_SZ / 4; k++) {
        float4 xv = xr[k];
        float4 wv = wr[k];
        acc += xv.x * wv.x + xv.y * wv.y + xv.z * wv.z + xv.w * wv.w;
    }
    enc[gi] = acc + bvec[q];
}

// ---------------- block-wide sum (result broadcast) ----------------
__device__ float blockAllSum(float v, float* scr) {
    #pragma unroll
    for (int o = 32; o > 0; o >>= 1) v += __shfl_down(v, o, 64);
    int lane = threadIdx.x & 63, w = threadIdx.x >> 6;
    __syncthreads();
    if (lane == 0) scr[w] = v;
    __syncthreads();
    return scr[0] + scr[1] + scr[2] + scr[3];
}

// ================= K2: batchnorm1 stats =================
__global__ void k_bnstats(const float* __restrict__ xm, float* __restrict__ mo,
                          float* __restrict__ ro, int ncols, int nrows) {
    __shared__ float scr[8];
    int j = blockIdx.x, t = threadIdx.x;
    float s = 0.f;
    for (int b = t; b < nrows; b += 256) s += xm[b * ncols + j];
    float mean = blockAllSum(s, scr) / (float)nrows;
    float s2 = 0.f;
    for (int b = t; b < nrows; b += 256) {
        float d = xm[b * ncols + j] - mean;
        s2 += d * d;
    }
    float var = blockAllSum(s2, scr) / (float)nrows;
    if (t == 0) {
        mo[j] = mean;
        ro[j] = 1.f / sqrtf(var + BN_EPS);
    }
}

// ================= K3: quantum circuit, register-resident state (NO private arrays) =================
// Amp index bit (11-q) holds qubit q.
// Layout A: idx = T<<4 | j
// Layout B: idx = T[7:4]<<8 | j<<4 | T[3:0]
// Layout C: idx = j<<8 | T
__device__ __forceinline__ int slotA(int T, int j) { return (T << 4) | (j ^ (T & 0xF)); }
__device__ __forceinline__ int slotB(int T, int j) {
    return ((T & 0xF0) << 4) | (j << 4) | ((T ^ j) & 0xF);
}
__device__ __forceinline__ int slotC(int T, int j) {
    return (j << 8) | (T & 0xF0) | (((T >> 4) ^ T) & 0xF);
}

// complex 2x2 on pair (A,B) with coeffs u00..u11 in scope
#define U_PAIR(A, B) { float2 a0 = A, a1 = B;                                   \
    A.x = u00r*a0.x - u00i*a0.y + u01r*a1.x - u01i*a1.y;                        \
    A.y = u00r*a0.y + u00i*a0.x + u01r*a1.y + u01i*a1.x;                        \
    B.x = u10r*a0.x - u10i*a0.y + u11r*a1.x - u11i*a1.y;                        \
    B.y = u10r*a0.y + u10i*a0.x + u11r*a1.y + u11i*a1.x; }

#define U_LOAD(uptr) const float* u_ = (uptr);                                   \
    float u00r=u_[0], u00i=u_[1], u01r=u_[2], u01i=u_[3],                        \
          u10r=u_[4], u10i=u_[5], u11r=u_[6], u11i=u_[7];

#define APPLY_U_K3(uptr) do { U_LOAD(uptr)                                      \
    U_PAIR(s0,s8) U_PAIR(s1,s9) U_PAIR(s2,s10) U_PAIR(s3,s11)                   \
    U_PAIR(s4,s12) U_PAIR(s5,s13) U_PAIR(s6,s14) U_PAIR(s7,s15) } while (0)
#define APPLY_U_K2(uptr) do { U_LOAD(uptr)                                      \
    U_PAIR(s0,s4) U_PAIR(s1,s5) U_PAIR(s2,s6) U_PAIR(s3,s7)                     \
    U_PAIR(s8,s12) U_PAIR(s9,s13) U_PAIR(s10,s14) U_PAIR(s11,s15) } while (0)
#define APPLY_U_K1(uptr) do { U_LOAD(uptr)                                      \
    U_PAIR(s0,s2) U_PAIR(s1,s3) U_PAIR(s4,s6) U_PAIR(s5,s7)                     \
    U_PAIR(s8,s10) U_PAIR(s9,s11) U_PAIR(s12,s14) U_PAIR(s13,s15) } while (0)
#define APPLY_U_K0(uptr) do { U_LOAD(uptr)                                      \
    U_PAIR(s0,s1) U_PAIR(s2,s3) U_PAIR(s4,s5) U_PAIR(s6,s7)                     \
    U_PAIR(s8,s9) U_PAIR(s10,s11) U_PAIR(s12,s13) U_PAIR(s14,s15) } while (0)

#define RY_PAIR(A, B) { float2 a0 = A, a1 = B;                                  \
    A.x = c_*a0.x - sn_*a1.x;  A.y = c_*a0.y - sn_*a1.y;                        \
    B.x = sn_*a0.x + c_*a1.x;  B.y = sn_*a0.y + c_*a1.y; }

// CRY with control bit KC=1, target bit KT (local): m has KC set, KT clear
#define CRY_32(cc, ss) do { float c_=(cc), sn_=(ss);                            \
    RY_PAIR(s8,s12) RY_PAIR(s9,s13) RY_PAIR(s10,s14) RY_PAIR(s11,s15) } while (0)
#define CRY_21(cc, ss) do { float c_=(cc), sn_=(ss);                            \
    RY_PAIR(s4,s6) RY_PAIR(s5,s7) RY_PAIR(s12,s14) RY_PAIR(s13,s15) } while (0)
#define CRY_10(cc, ss) do { float c_=(cc), sn_=(ss);                            \
    RY_PAIR(s2,s3) RY_PAIR(s6,s7) RY_PAIR(s10,s11) RY_PAIR(s14,s15) } while (0)
#define RYALL_K3(cc, ss) do { float c_=(cc), sn_=(ss);                          \
    RY_PAIR(s0,s8) RY_PAIR(s1,s9) RY_PAIR(s2,s10) RY_PAIR(s3,s11)               \
    RY_PAIR(s4,s12) RY_PAIR(s5,s13) RY_PAIR(s6,s14) RY_PAIR(s7,s15) } while (0)

#define XPOSE(SW, SR) do {                                                      \
    __syncthreads();                                                            \
    xch[SW(T,0)]=s0;  xch[SW(T,1)]=s1;  xch[SW(T,2)]=s2;  xch[SW(T,3)]=s3;      \
    xch[SW(T,4)]=s4;  xch[SW(T,5)]=s5;  xch[SW(T,6)]=s6;  xch[SW(T,7)]=s7;      \
    xch[SW(T,8)]=s8;  xch[SW(T,9)]=s9;  xch[SW(T,10)]=s10; xch[SW(T,11)]=s11;   \
    xch[SW(T,12)]=s12; xch[SW(T,13)]=s13; xch[SW(T,14)]=s14; xch[SW(T,15)]=s15; \
    __syncthreads();                                                            \
    s0=xch[SR(T,0)];  s1=xch[SR(T,1)];  s2=xch[SR(T,2)];  s3=xch[SR(T,3)];      \
    s4=xch[SR(T,4)];  s5=xch[SR(T,5)];  s6=xch[SR(T,6)];  s7=xch[SR(T,7)];      \
    s8=xch[SR(T,8)];  s9=xch[SR(T,9)];  s10=xch[SR(T,10)]; s11=xch[SR(T,11)];   \
    s12=xch[SR(T,12)]; s13=xch[SR(T,13)]; s14=xch[SR(T,14)]; s15=xch[SR(T,15)]; \
} while (0)

#define INITJ(j) make_float2(f * (((j)&8)?a81:a80) * (((j)&4)?a91:a90)          \
                               * (((j)&2)?aa1:aa0) * (((j)&1)?ab1:ab0), 0.f)

#define PRJ(S) ((S).x*(S).x + (S).y*(S).y)

#define WREDUCE(v) { v += __shfl_down(v,32,64); v += __shfl_down(v,16,64);      \
    v += __shfl_down(v,8,64); v += __shfl_down(v,4,64);                         \
    v += __shfl_down(v,2,64); v += __shfl_down(v,1,64); }

__launch_bounds__(256, 4)
__global__ void k_quantum(const float* __restrict__ enc,
                          const float* __restrict__ bn1m, const float* __restrict__ bn1r,
                          const float* __restrict__ g1, const float* __restrict__ b1,
                          const float* __restrict__ gU, const float* __restrict__ gC,
                          float* __restrict__ probs) {
    __shared__ float2 xch[NST];                                  // 32 KB
    __shared__ float  gbuf[DEPTH * NQ * 8 + DEPTH * (NQ - 1) * 2];
    __shared__ float  qv[NQ][2];
    __shared__ float  hbuf[NQ];

    int T = threadIdx.x, b = blockIdx.x;

    for (int i = T; i < 354; i += 256) gbuf[i] = (i < 288) ? gU[i] : gC[i - 288];

    if (T < NQ) {
        float e = enc[b * NQ + T];
        hbuf[T] = tanhf(g1[T] * (e - bn1m[T]) * bn1r[T] + b1[T]);
    }
    __syncthreads();
    if (T < NQ) {
        float n2 = 0.f;
        #pragma unroll
        for (int i = 0; i < NQ; i++) n2 += hbuf[i] * hbuf[i];
        float norm = sqrtf(n2);
        float h = hbuf[T];
        float a = (norm > 0.f) ? h / fmaxf(norm, 1e-30f) : h;
        float amp = fminf(fabsf(a), 1.f);
        float ch  = sqrtf(fmaxf(1.f - amp * amp, 0.f));
        qv[T][0] = ch;
        qv[T][1] = (a < 0.f) ? -amp : amp;
    }
    __syncthreads();

    // ---- initial product state, layout A ----
    float f = 1.f;
    #pragma unroll
    for (int q = 0; q < 8; q++) f *= qv[q][(T >> (7 - q)) & 1];
    float a80 = qv[8][0],  a81 = qv[8][1];
    float a90 = qv[9][0],  a91 = qv[9][1];
    float aa0 = qv[10][0], aa1 = qv[10][1];
    float ab0 = qv[11][0], ab1 = qv[11][1];
    float2 s0 = INITJ(0),  s1 = INITJ(1),  s2 = INITJ(2),  s3 = INITJ(3);
    float2 s4 = INITJ(4),  s5 = INITJ(5),  s6 = INITJ(6),  s7 = INITJ(7);
    float2 s8 = INITJ(8),  s9 = INITJ(9),  s10 = INITJ(10), s11 = INITJ(11);
    float2 s12 = INITJ(12), s13 = INITJ(13), s14 = INITJ(14), s15 = INITJ(15);

    #pragma unroll 1
    for (int l = 0; l < DEPTH; l++) {
        const float* UL = &gbuf[l * NQ * 8];
        const float* CL = &gbuf[288 + l * (NQ - 1) * 2];
        // layout A: U on qubits 8..11 (local bits 3..0)
        APPLY_U_K3(UL + 8 * 8);
        APPLY_U_K2(UL + 9 * 8);
        APPLY_U_K1(UL + 10 * 8);
        APPLY_U_K0(UL + 11 * 8);
        XPOSE(slotA, slotB);
        // layout B: U on qubits 4..7
        APPLY_U_K3(UL + 4 * 8);
        APPLY_U_K2(UL + 5 * 8);
        APPLY_U_K1(UL + 6 * 8);
        APPLY_U_K0(UL + 7 * 8);
        XPOSE(slotB, slotC);
        // layout C: U on qubits 0..3; CRY0..2
        APPLY_U_K3(UL + 0 * 8);
        APPLY_U_K2(UL + 1 * 8);
        APPLY_U_K1(UL + 2 * 8);
        APPLY_U_K0(UL + 3 * 8);
        CRY_32(CL[0], CL[1]);      // CRY0
        CRY_21(CL[2], CL[3]);      // CRY1
        CRY_10(CL[4], CL[5]);      // CRY2
        XPOSE(slotC, slotB);
        // layout B: CRY3 (control = idx bit 8 = T&16), CRY4..6
        if (T & 16) RYALL_K3(CL[6], CL[7]);
        CRY_32(CL[8], CL[9]);      // CRY4
        CRY_21(CL[10], CL[11]);    // CRY5
        CRY_10(CL[12], CL[13]);    // CRY6
        XPOSE(slotB, slotA);
        // layout A: CRY7 (control = idx bit 4 = T&1), CRY8..10
        if (T & 1) RYALL_K3(CL[14], CL[15]);
        CRY_32(CL[16], CL[17]);    // CRY8
        CRY_21(CL[18], CL[19]);    // CRY9
        CRY_10(CL[20], CL[21]);    // CRY10
    }

    // ---- marginals, layout A: idx = T<<4 | j ----
    float p0 = PRJ(s0),  p1 = PRJ(s1),  p2 = PRJ(s2),  p3 = PRJ(s3);
    float p4 = PRJ(s4),  p5 = PRJ(s5),  p6 = PRJ(s6),  p7 = PRJ(s7);
    float p8 = PRJ(s8),  p9 = PRJ(s9),  p10 = PRJ(s10), p11 = PRJ(s11);
    float p12 = PRJ(s12), p13 = PRJ(s13), p14 = PRJ(s14), p15 = PRJ(s15);
    float tot = p0+p1+p2+p3+p4+p5+p6+p7+p8+p9+p10+p11+p12+p13+p14+p15;
    float r8  = p8+p9+p10+p11+p12+p13+p14+p15;            // j bit3 -> qubit 8
    float r9  = p4+p5+p6+p7+p12+p13+p14+p15;              // j bit2 -> qubit 9
    float r10 = p2+p3+p6+p7+p10+p11+p14+p15;              // j bit1 -> qubit 10
    float r11 = p1+p3+p5+p7+p9+p11+p13+p15;               // j bit0 -> qubit 11
    float r0 = (T & 128) ? tot : 0.f;                     // qubit 0 = T bit 7
    float r1 = (T & 64)  ? tot : 0.f;
    float r2 = (T & 32)  ? tot : 0.f;
    float r3 = (T & 16)  ? tot : 0.f;
    float r4 = (T & 8)   ? tot : 0.f;
    float r5 = (T & 4)   ? tot : 0.f;
    float r6 = (T & 2)   ? tot : 0.f;
    float r7 = (T & 1)   ? tot : 0.f;

    WREDUCE(r0) WREDUCE(r1) WREDUCE(r2) WREDUCE(r3) WREDUCE(r4) WREDUCE(r5)
    WREDUCE(r6) WREDUCE(r7) WREDUCE(r8) WREDUCE(r9) WREDUCE(r10) WREDUCE(r11)

    __syncthreads();                     // xch no longer needed as state
    float* red = (float*)xch;
    int lane = T & 63, w = T >> 6;
    if (lane == 0) {
        float* rr = red + w * NQ;
        rr[0]=r0; rr[1]=r1; rr[2]=r2; rr[3]=r3; rr[4]=r4; rr[5]=r5;
        rr[6]=r6; rr[7]=r7; rr[8]=r8; rr[9]=r9; rr[10]=r10; rr[11]=r11;
    }
    __syncthreads();
    if (T < NQ) probs[b * NQ + T] = red[T] + red[NQ + T] + red[2 * NQ + T] + red[3 * NQ + T];
}

// ================= K4: prob moments -> pmean + cov (one pass) =================
__global__ void k_pcov(const float* __restrict__ probs, float* __restrict__ pmean,
                       float* __restrict__ cov) {
    __shared__ float scr[8];
    int blk = blockIdx.x;             // 0..143
    int q = blk / NQ, q2 = blk % NQ;
    int t = threadIdx.x;
    float sx = 0.f, sy = 0.f, sxy = 0.f;
    for (int b = t; b < BATCH; b += 256) {
        float xv = probs[b * NQ + q];
        float yv = probs[b * NQ + q2];
        sx += xv; sy += yv; sxy += xv * yv;
    }
    float SX  = blockAllSum(sx,  scr);
    float SY  = blockAllSum(sy,  scr);
    float SXY = blockAllSum(sxy, scr);
    if (t == 0) {
        float mx = SX / (float)BATCH, my = SY / (float)BATCH;
        cov[blk] = SXY / (float)BATCH - mx * my;
        if (q == q2) pmean[q] = mx;
    }
}

// ================= K5: final decode + BN2 =================
__global__ void k_final(const float* __restrict__ probs, const float* __restrict__ pmean,
                        const float* __restrict__ cov, const float* __restrict__ dw,
                        const float* __restrict__ g2, const float* __restrict__ b2,
                        float* __restrict__ out) {
    __shared__ float cv[NQ * NQ];
    __shared__ float cp[NQ];
    int b = blockIdx.x, t = threadIdx.x;
    if (t < NQ * NQ) cv[t] = cov[t];
    if (t < NQ) cp[t] = probs[b * NQ + t] - pmean[t];
    __syncthreads();
    float w[NQ];
    #pragma unroll
    for (int q = 0; q < NQ; q++) w[q] = dw[t * NQ + q];
    float var = 0.f, acc = 0.f;
    #pragma unroll
    for (int q = 0; q < NQ; q++) {
        float a = 0.f;
        #pragma unroll
        for (int q2 = 0; q2 < NQ; q2++) a += cv[q * NQ + q2] * w[q2];
        var += w[q] * a;
        acc += cp[q] * w[q];
    }
    out[b * OUT_SZ + t] = acc * (1.f / sqrtf(var + BN_EPS)) * g2[t] + b2[t];
}

extern "C" void kernel_launch(void* const* d_in, const int* in_sizes, int n_in,
                              void* d_out, int out_size, void* d_ws, size_t ws_size,
                              hipStream_t stream) {
    const float* x     = (const float*)d_in[0];
    const float* enc_w = (const float*)d_in[1];
    const float* enc_b = (const float*)d_in[2];
    const float* rot   = (const float*)d_in[3];
    const float* ent   = (const float*)d_in[4];
    const float* dec_w = (const float*)d_in[5];
    // d_in[6] = dec_b — cancels inside BN2
    const float* g1    = (const float*)d_in[7];
    const float* b1    = (const float*)d_in[8];
    const float* g2    = (const float*)d_in[9];
    const float* b2    = (const float*)d_in[10];

    float* ws    = (float*)d_ws;
    float* enc   = ws + OFF_ENC;
    float* bn1m  = ws + OFF_BN1M;
    float* bn1r  = ws + OFF_BN1R;
    float* gU    = ws + OFF_GU;
    float* gC    = ws + OFF_GC;
    float* prb   = ws + OFF_PROBS;
    float* pmean = ws + OFF_PMEAN;
    float* cov   = ws + OFF_COV;

    hipLaunchKernelGGL(k_encode, dim3(193), dim3(256), 0, stream,
                       x, enc_w, enc_b, rot, ent, enc, gU, gC);
    hipLaunchKernelGGL(k_bnstats, dim3(NQ), dim3(256), 0, stream, enc, bn1m, bn1r, NQ, BATCH);
    hipLaunchKernelGGL(k_quantum, dim3(BATCH), dim3(256), 0, stream,
                       enc, bn1m, bn1r, g1, b1, gU, gC, prb);
    hipLaunchKernelGGL(k_pcov, dim3(NQ * NQ), dim3(256), 0, stream, prb, pmean, cov);
    hipLaunchKernelGGL(k_final, dim3(BATCH), dim3(OUT_SZ), 0, stream,
                       prb, pmean, cov, dec_w, g2, b2, (float*)d_out);
}

// Round 6
// 352.570 us; speedup vs baseline: 1.1837x; 1.1837x over previous
//
#include <hip/hip_runtime.h>

#define BATCH   4096
#define IN_SZ   512
#define NQ      12
#define OUT_SZ  256
#define DEPTH   3
#define NST     4096   // 2^NQ
#define BN_EPS  1e-5f

// ---- ws layout (in floats) ----
#define OFF_ENC    0            // 4096*12 = 49152
#define OFF_BN1M   49152
#define OFF_BN1R   49168
#define OFF_GU     49184        // 288
#define OFF_GC     49472        // 66 (pad 96)
#define OFF_PROBS  49568        // 49152
#define OFF_PMEAN  98720
#define OFF_COV    98736        // 144

// ================= K1: encode (+ fused gate precompute in block 192) =================
__global__ void k_encode(const float* __restrict__ x, const float* __restrict__ w,
                         const float* __restrict__ bvec,
                         const float* __restrict__ rot, const float* __restrict__ ent,
                         float* __restrict__ enc, float* __restrict__ gU, float* __restrict__ gC) {
    if (blockIdx.x == 192) {
        int t = threadIdx.x;
        if (t < DEPTH * NQ) {
            float ax = rot[t * 3 + 0] * 0.5f;
            float ay = rot[t * 3 + 1] * 0.5f;
            float az = rot[t * 3 + 2] * 0.5f;
            float cx = cosf(ax), sx = sinf(ax);
            float cy = cosf(ay), sy = sinf(ay);
            float cz = cosf(az), sz = sinf(az);
            float m00r =  cy * cx, m00i =  sy * sx;
            float m01r = -sy * cx, m01i = -cy * sx;
            float m10r =  sy * cx, m10i = -cy * sx;
            float m11r =  cy * cx, m11i = -sy * sx;
            float* o = gU + t * 8;
            o[0] = cz * m00r + sz * m00i;  o[1] = cz * m00i - sz * m00r;
            o[2] = cz * m01r + sz * m01i;  o[3] = cz * m01i - sz * m01r;
            o[4] = cz * m10r - sz * m10i;  o[5] = cz * m10i + sz * m10r;
            o[6] = cz * m11r - sz * m11i;  o[7] = cz * m11i + sz * m11r;
        }
        if (t >= 64 && t - 64 < DEPTH * (NQ - 1)) {
            int i = t - 64;
            float th = ent[i] * 0.5f;
            gC[i * 2 + 0] = cosf(th);
            gC[i * 2 + 1] = sinf(th);
        }
        return;
    }
    int gi = blockIdx.x * 256 + threadIdx.x;
    int row = gi / NQ;
    int q   = gi - row * NQ;
    const float4* xr = (const float4*)(x + row * IN_SZ);
    const float4* wr = (const float4*)(w + q * IN_SZ);
    float acc = 0.f;
    for (int k = 0; k < IN_SZ / 4; k++) {
        float4 xv = xr[k];
        float4 wv = wr[k];
        acc += xv.x * wv.x + xv.y * wv.y + xv.z * wv.z + xv.w * wv.w;
    }
    enc[gi] = acc + bvec[q];
}

// ---------------- block-wide sum (result broadcast) ----------------
__device__ float blockAllSum(float v, float* scr) {
    #pragma unroll
    for (int o = 32; o > 0; o >>= 1) v += __shfl_down(v, o, 64);
    int lane = threadIdx.x & 63, w = threadIdx.x >> 6;
    __syncthreads();
    if (lane == 0) scr[w] = v;
    __syncthreads();
    return scr[0] + scr[1] + scr[2] + scr[3];
}

// ================= K2: batchnorm1 stats =================
__global__ void k_bnstats(const float* __restrict__ xm, float* __restrict__ mo,
                          float* __restrict__ ro, int ncols, int nrows) {
    __shared__ float scr[8];
    int j = blockIdx.x, t = threadIdx.x;
    float s = 0.f;
    for (int b = t; b < nrows; b += 256) s += xm[b * ncols + j];
    float mean = blockAllSum(s, scr) / (float)nrows;
    float s2 = 0.f;
    for (int b = t; b < nrows; b += 256) {
        float d = xm[b * ncols + j] - mean;
        s2 += d * d;
    }
    float var = blockAllSum(s2, scr) / (float)nrows;
    if (t == 0) {
        mo[j] = mean;
        ro[j] = 1.f / sqrtf(var + BN_EPS);
    }
}

// ================= K3: quantum circuit — windowed in-place LDS passes =================
// Canonical amp index: qubit q at bit (11-q). LDS slot swizzle: slot = idx ^ ((idx>>4)&15).
// Window A: local nibble = idx bits 3..0  (qubits 8..11); thread supplies bits 11..4 = T
// Window B: local nibble = idx bits 7..4  (qubits 4..7);  T[7:4]->bits 11..8, T[3:0]->bits 3..0
// Window C: local nibble = idx bits 11..8 (qubits 0..3);  T -> bits 7..0
#define SLA(m) ((T << 4) | ((m) ^ (T & 15)))
#define SLB(m) (((T & 0xF0) << 4) | ((m) << 4) | ((T ^ (m)) & 15))
#define SLC(m) (((m) << 8) | (T & 0xF0) | ((T ^ (T >> 4)) & 15))

#define LOADW(SL) do {                                                          \
    s0=xch[SL(0)];  s1=xch[SL(1)];  s2=xch[SL(2)];  s3=xch[SL(3)];              \
    s4=xch[SL(4)];  s5=xch[SL(5)];  s6=xch[SL(6)];  s7=xch[SL(7)];              \
    s8=xch[SL(8)];  s9=xch[SL(9)];  s10=xch[SL(10)]; s11=xch[SL(11)];           \
    s12=xch[SL(12)]; s13=xch[SL(13)]; s14=xch[SL(14)]; s15=xch[SL(15)]; } while (0)
#define STORW(SL) do {                                                          \
    xch[SL(0)]=s0;  xch[SL(1)]=s1;  xch[SL(2)]=s2;  xch[SL(3)]=s3;              \
    xch[SL(4)]=s4;  xch[SL(5)]=s5;  xch[SL(6)]=s6;  xch[SL(7)]=s7;              \
    xch[SL(8)]=s8;  xch[SL(9)]=s9;  xch[SL(10)]=s10; xch[SL(11)]=s11;           \
    xch[SL(12)]=s12; xch[SL(13)]=s13; xch[SL(14)]=s14; xch[SL(15)]=s15; } while (0)

// complex 2x2 on pair (A,B) with coeffs u00..u11 in scope
#define U_PAIR(A, B) { float2 a0 = A, a1 = B;                                   \
    A.x = u00r*a0.x - u00i*a0.y + u01r*a1.x - u01i*a1.y;                        \
    A.y = u00r*a0.y + u00i*a0.x + u01r*a1.y + u01i*a1.x;                        \
    B.x = u10r*a0.x - u10i*a0.y + u11r*a1.x - u11i*a1.y;                        \
    B.y = u10r*a0.y + u10i*a0.x + u11r*a1.y + u11i*a1.x; }

#define U_LOAD(uptr) const float* u_ = (uptr);                                   \
    float u00r=u_[0], u00i=u_[1], u01r=u_[2], u01i=u_[3],                        \
          u10r=u_[4], u10i=u_[5], u11r=u_[6], u11i=u_[7];

#define APPLY_U_K3(uptr) do { U_LOAD(uptr)                                      \
    U_PAIR(s0,s8) U_PAIR(s1,s9) U_PAIR(s2,s10) U_PAIR(s3,s11)                   \
    U_PAIR(s4,s12) U_PAIR(s5,s13) U_PAIR(s6,s14) U_PAIR(s7,s15) } while (0)
#define APPLY_U_K2(uptr) do { U_LOAD(uptr)                                      \
    U_PAIR(s0,s4) U_PAIR(s1,s5) U_PAIR(s2,s6) U_PAIR(s3,s7)                     \
    U_PAIR(s8,s12) U_PAIR(s9,s13) U_PAIR(s10,s14) U_PAIR(s11,s15) } while (0)
#define APPLY_U_K1(uptr) do { U_LOAD(uptr)                                      \
    U_PAIR(s0,s2) U_PAIR(s1,s3) U_PAIR(s4,s6) U_PAIR(s5,s7)                     \
    U_PAIR(s8,s10) U_PAIR(s9,s11) U_PAIR(s12,s14) U_PAIR(s13,s15) } while (0)
#define APPLY_U_K0(uptr) do { U_LOAD(uptr)                                      \
    U_PAIR(s0,s1) U_PAIR(s2,s3) U_PAIR(s4,s5) U_PAIR(s6,s7)                     \
    U_PAIR(s8,s9) U_PAIR(s10,s11) U_PAIR(s12,s13) U_PAIR(s14,s15) } while (0)

#define RY_PAIR(A, B) { float2 a0 = A, a1 = B;                                  \
    A.x = c_*a0.x - sn_*a1.x;  A.y = c_*a0.y - sn_*a1.y;                        \
    B.x = sn_*a0.x + c_*a1.x;  B.y = sn_*a0.y + c_*a1.y; }

#define CRY_32(cc, ss) do { float c_=(cc), sn_=(ss);                            \
    RY_PAIR(s8,s12) RY_PAIR(s9,s13) RY_PAIR(s10,s14) RY_PAIR(s11,s15) } while (0)
#define CRY_21(cc, ss) do { float c_=(cc), sn_=(ss);                            \
    RY_PAIR(s4,s6) RY_PAIR(s5,s7) RY_PAIR(s12,s14) RY_PAIR(s13,s15) } while (0)
#define CRY_10(cc, ss) do { float c_=(cc), sn_=(ss);                            \
    RY_PAIR(s2,s3) RY_PAIR(s6,s7) RY_PAIR(s10,s11) RY_PAIR(s14,s15) } while (0)
#define RYALL_K3(cc, ss) do { float c_=(cc), sn_=(ss);                          \
    RY_PAIR(s0,s8) RY_PAIR(s1,s9) RY_PAIR(s2,s10) RY_PAIR(s3,s11)               \
    RY_PAIR(s4,s12) RY_PAIR(s5,s13) RY_PAIR(s6,s14) RY_PAIR(s7,s15) } while (0)

#define INITJ(j) make_float2(f * (((j)&8)?a81:a80) * (((j)&4)?a91:a90)          \
                               * (((j)&2)?aa1:aa0) * (((j)&1)?ab1:ab0), 0.f)
#define PRJ(S) ((S).x*(S).x + (S).y*(S).y)
#define WREDUCE(v) { v += __shfl_down(v,32,64); v += __shfl_down(v,16,64);      \
    v += __shfl_down(v,8,64); v += __shfl_down(v,4,64);                         \
    v += __shfl_down(v,2,64); v += __shfl_down(v,1,64); }

__launch_bounds__(256)
__global__ void k_quantum(const float* __restrict__ enc,
                          const float* __restrict__ bn1m, const float* __restrict__ bn1r,
                          const float* __restrict__ g1, const float* __restrict__ b1,
                          const float* __restrict__ gU, const float* __restrict__ gC,
                          float* __restrict__ probs) {
    __shared__ float2 xch[NST];                                  // 32 KB
    __shared__ float  gbuf[DEPTH * NQ * 8 + DEPTH * (NQ - 1) * 2];
    __shared__ float  qv[NQ][2];
    __shared__ float  hbuf[NQ];

    int T = threadIdx.x, b = blockIdx.x;

    for (int i = T; i < 354; i += 256) gbuf[i] = (i < 288) ? gU[i] : gC[i - 288];

    if (T < NQ) {
        float e = enc[b * NQ + T];
        hbuf[T] = tanhf(g1[T] * (e - bn1m[T]) * bn1r[T] + b1[T]);
    }
    __syncthreads();
    if (T < NQ) {
        float n2 = 0.f;
        #pragma unroll
        for (int i = 0; i < NQ; i++) n2 += hbuf[i] * hbuf[i];
        float norm = sqrtf(n2);
        float h = hbuf[T];
        float a = (norm > 0.f) ? h / fmaxf(norm, 1e-30f) : h;
        float amp = fminf(fabsf(a), 1.f);
        float ch  = sqrtf(fmaxf(1.f - amp * amp, 0.f));
        qv[T][0] = ch;
        qv[T][1] = (a < 0.f) ? -amp : amp;
    }
    __syncthreads();

    float2 s0, s1, s2, s3, s4, s5, s6, s7, s8, s9, s10, s11, s12, s13, s14, s15;

    // ---- init (window A order) + U on qubits 8..11 of layer 0, store ----
    {
        float f = 1.f;
        #pragma unroll
        for (int q = 0; q < 8; q++) f *= qv[q][(T >> (7 - q)) & 1];
        float a80 = qv[8][0],  a81 = qv[8][1];
        float a90 = qv[9][0],  a91 = qv[9][1];
        float aa0 = qv[10][0], aa1 = qv[10][1];
        float ab0 = qv[11][0], ab1 = qv[11][1];
        s0 = INITJ(0);  s1 = INITJ(1);  s2 = INITJ(2);  s3 = INITJ(3);
        s4 = INITJ(4);  s5 = INITJ(5);  s6 = INITJ(6);  s7 = INITJ(7);
        s8 = INITJ(8);  s9 = INITJ(9);  s10 = INITJ(10); s11 = INITJ(11);
        s12 = INITJ(12); s13 = INITJ(13); s14 = INITJ(14); s15 = INITJ(15);
        const float* U0 = gbuf;
        APPLY_U_K3(U0 + 8 * 8);
        APPLY_U_K2(U0 + 9 * 8);
        APPLY_U_K1(U0 + 10 * 8);
        APPLY_U_K0(U0 + 11 * 8);
        STORW(SLA);
    }

    #pragma unroll 1
    for (int l = 0; l < DEPTH; l++) {
        const float* UL = gbuf + l * 96;
        const float* CL = gbuf + 288 + l * 22;
        // ---- window B: U on qubits 4..7 ----
        __syncthreads();
        LOADW(SLB);
        APPLY_U_K3(UL + 4 * 8);
        APPLY_U_K2(UL + 5 * 8);
        APPLY_U_K1(UL + 6 * 8);
        APPLY_U_K0(UL + 7 * 8);
        STORW(SLB);
        // ---- window C: U on qubits 0..3; CRY0..2 ----
        __syncthreads();
        LOADW(SLC);
        APPLY_U_K3(UL + 0 * 8);
        APPLY_U_K2(UL + 1 * 8);
        APPLY_U_K1(UL + 2 * 8);
        APPLY_U_K0(UL + 3 * 8);
        CRY_32(CL[0], CL[1]);
        CRY_21(CL[2], CL[3]);
        CRY_10(CL[4], CL[5]);
        STORW(SLC);
        // ---- window B: CRY3 (control = idx bit 8 = T&16), CRY4..6 ----
        __syncthreads();
        LOADW(SLB);
        if (T & 16) RYALL_K3(CL[6], CL[7]);
        CRY_32(CL[8], CL[9]);
        CRY_21(CL[10], CL[11]);
        CRY_10(CL[12], CL[13]);
        STORW(SLB);
        // ---- window A: CRY7 (control = idx bit 4 = T&1), CRY8..10 [+ next layer's U8..11] ----
        __syncthreads();
        LOADW(SLA);
        if (T & 1) RYALL_K3(CL[14], CL[15]);
        CRY_32(CL[16], CL[17]);
        CRY_21(CL[18], CL[19]);
        CRY_10(CL[20], CL[21]);
        if (l < DEPTH - 1) {
            const float* UN = gbuf + (l + 1) * 96;
            APPLY_U_K3(UN + 8 * 8);
            APPLY_U_K2(UN + 9 * 8);
            APPLY_U_K1(UN + 10 * 8);
            APPLY_U_K0(UN + 11 * 8);
            STORW(SLA);
        }
    }

    // ---- marginals from registers (window A: idx = T<<4 | m) ----
    float p0 = PRJ(s0),  p1 = PRJ(s1),  p2 = PRJ(s2),  p3 = PRJ(s3);
    float p4 = PRJ(s4),  p5 = PRJ(s5),  p6 = PRJ(s6),  p7 = PRJ(s7);
    float p8 = PRJ(s8),  p9 = PRJ(s9),  p10 = PRJ(s10), p11 = PRJ(s11);
    float p12 = PRJ(s12), p13 = PRJ(s13), p14 = PRJ(s14), p15 = PRJ(s15);
    float tot = p0+p1+p2+p3+p4+p5+p6+p7+p8+p9+p10+p11+p12+p13+p14+p15;
    float r8  = p8+p9+p10+p11+p12+p13+p14+p15;
    float r9  = p4+p5+p6+p7+p12+p13+p14+p15;
    float r10 = p2+p3+p6+p7+p10+p11+p14+p15;
    float r11 = p1+p3+p5+p7+p9+p11+p13+p15;
    float r0 = (T & 128) ? tot : 0.f;
    float r1 = (T & 64)  ? tot : 0.f;
    float r2 = (T & 32)  ? tot : 0.f;
    float r3 = (T & 16)  ? tot : 0.f;
    float r4 = (T & 8)   ? tot : 0.f;
    float r5 = (T & 4)   ? tot : 0.f;
    float r6 = (T & 2)   ? tot : 0.f;
    float r7 = (T & 1)   ? tot : 0.f;

    WREDUCE(r0) WREDUCE(r1) WREDUCE(r2) WREDUCE(r3) WREDUCE(r4) WREDUCE(r5)
    WREDUCE(r6) WREDUCE(r7) WREDUCE(r8) WREDUCE(r9) WREDUCE(r10) WREDUCE(r11)

    __syncthreads();
    float* red = (float*)xch;
    int lane = T & 63, w = T >> 6;
    if (lane == 0) {
        float* rr = red + w * NQ;
        rr[0]=r0; rr[1]=r1; rr[2]=r2; rr[3]=r3; rr[4]=r4; rr[5]=r5;
        rr[6]=r6; rr[7]=r7; rr[8]=r8; rr[9]=r9; rr[10]=r10; rr[11]=r11;
    }
    __syncthreads();
    if (T < NQ) probs[b * NQ + T] = red[T] + red[NQ + T] + red[2 * NQ + T] + red[3 * NQ + T];
}

// ================= K4: prob moments -> pmean + cov (one pass) =================
__global__ void k_pcov(const float* __restrict__ probs, float* __restrict__ pmean,
                       float* __restrict__ cov) {
    __shared__ float scr[8];
    int blk = blockIdx.x;             // 0..143
    int q = blk / NQ, q2 = blk % NQ;
    int t = threadIdx.x;
    float sx = 0.f, sy = 0.f, sxy = 0.f;
    for (int b = t; b < BATCH; b += 256) {
        float xv = probs[b * NQ + q];
        float yv = probs[b * NQ + q2];
        sx += xv; sy += yv; sxy += xv * yv;
    }
    float SX  = blockAllSum(sx,  scr);
    float SY  = blockAllSum(sy,  scr);
    float SXY = blockAllSum(sxy, scr);
    if (t == 0) {
        float mx = SX / (float)BATCH, my = SY / (float)BATCH;
        cov[blk] = SXY / (float)BATCH - mx * my;
        if (q == q2) pmean[q] = mx;
    }
}

// ================= K5: final decode + BN2 =================
__global__ void k_final(const float* __restrict__ probs, const float* __restrict__ pmean,
                        const float* __restrict__ cov, const float* __restrict__ dw,
                        const float* __restrict__ g2, const float* __restrict__ b2,
                        float* __restrict__ out) {
    __shared__ float cv[NQ * NQ];
    __shared__ float cp[NQ];
    int b = blockIdx.x, t = threadIdx.x;
    if (t < NQ * NQ) cv[t] = cov[t];
    if (t < NQ) cp[t] = probs[b * NQ + t] - pmean[t];
    __syncthreads();
    float w[NQ];
    #pragma unroll
    for (int q = 0; q < NQ; q++) w[q] = dw[t * NQ + q];
    float var = 0.f, acc = 0.f;
    #pragma unroll
    for (int q = 0; q < NQ; q++) {
        float a = 0.f;
        #pragma unroll
        for (int q2 = 0; q2 < NQ; q2++) a += cv[q * NQ + q2] * w[q2];
        var += w[q] * a;
        acc += cp[q] * w[q];
    }
    out[b * OUT_SZ + t] = acc * (1.f / sqrtf(var + BN_EPS)) * g2[t] + b2[t];
}

extern "C" void kernel_launch(void* const* d_in, const int* in_sizes, int n_in,
                              void* d_out, int out_size, void* d_ws, size_t ws_size,
                              hipStream_t stream) {
    const float* x     = (const float*)d_in[0];
    const float* enc_w = (const float*)d_in[1];
    const float* enc_b = (const float*)d_in[2];
    const float* rot   = (const float*)d_in[3];
    const float* ent   = (const float*)d_in[4];
    const float* dec_w = (const float*)d_in[5];
    // d_in[6] = dec_b — cancels inside BN2
    const float* g1    = (const float*)d_in[7];
    const float* b1    = (const float*)d_in[8];
    const float* g2    = (const float*)d_in[9];
    const float* b2    = (const float*)d_in[10];

    float* ws    = (float*)d_ws;
    float* enc   = ws + OFF_ENC;
    float* bn1m  = ws + OFF_BN1M;
    float* bn1r  = ws + OFF_BN1R;
    float* gU    = ws + OFF_GU;
    float* gC    = ws + OFF_GC;
    float* prb   = ws + OFF_PROBS;
    float* pmean = ws + OFF_PMEAN;
    float* cov   = ws + OFF_COV;

    hipLaunchKernelGGL(k_encode, dim3(193), dim3(256), 0, stream,
                       x, enc_w, enc_b, rot, ent, enc, gU, gC);
    hipLaunchKernelGGL(k_bnstats, dim3(NQ), dim3(256), 0, stream, enc, bn1m, bn1r, NQ, BATCH);
    hipLaunchKernelGGL(k_quantum, dim3(BATCH), dim3(256), 0, stream,
                       enc, bn1m, bn1r, g1, b1, gU, gC, prb);
    hipLaunchKernelGGL(k_pcov, dim3(NQ * NQ), dim3(256), 0, stream, prb, pmean, cov);
    hipLaunchKernelGGL(k_final, dim3(BATCH), dim3(OUT_SZ), 0, stream,
                       prb, pmean, cov, dec_w, g2, b2, (float*)d_out);
}

// Round 7
// 350.465 us; speedup vs baseline: 1.1908x; 1.0060x over previous
//
#include <hip/hip_runtime.h>

#define BATCH   4096
#define IN_SZ   512
#define NQ      12
#define OUT_SZ  256
#define DEPTH   3
#define NST     4096   // 2^NQ
#define BN_EPS  1e-5f

// ---- ws layout (in floats) ----
#define OFF_ENC    0            // 4096*12 = 49152
#define OFF_BN1M   49152
#define OFF_BN1R   49168
#define OFF_GU     49184        // 288
#define OFF_GC     49472        // 66 (pad 96)
#define OFF_PROBS  49568        // 49152
#define OFF_PMEAN  98720
#define OFF_COV    98736        // 144

// ================= K1: encode (+ fused gate precompute in block 192) =================
__global__ void k_encode(const float* __restrict__ x, const float* __restrict__ w,
                         const float* __restrict__ bvec,
                         const float* __restrict__ rot, const float* __restrict__ ent,
                         float* __restrict__ enc, float* __restrict__ gU, float* __restrict__ gC) {
    if (blockIdx.x == 192) {
        int t = threadIdx.x;
        if (t < DEPTH * NQ) {
            float ax = rot[t * 3 + 0] * 0.5f;
            float ay = rot[t * 3 + 1] * 0.5f;
            float az = rot[t * 3 + 2] * 0.5f;
            float cx = cosf(ax), sx = sinf(ax);
            float cy = cosf(ay), sy = sinf(ay);
            float cz = cosf(az), sz = sinf(az);
            float m00r =  cy * cx, m00i =  sy * sx;
            float m01r = -sy * cx, m01i = -cy * sx;
            float m10r =  sy * cx, m10i = -cy * sx;
            float m11r =  cy * cx, m11i = -sy * sx;
            float* o = gU + t * 8;
            o[0] = cz * m00r + sz * m00i;  o[1] = cz * m00i - sz * m00r;
            o[2] = cz * m01r + sz * m01i;  o[3] = cz * m01i - sz * m01r;
            o[4] = cz * m10r - sz * m10i;  o[5] = cz * m10i + sz * m10r;
            o[6] = cz * m11r - sz * m11i;  o[7] = cz * m11i + sz * m11r;
        }
        if (t >= 64 && t - 64 < DEPTH * (NQ - 1)) {
            int i = t - 64;
            float th = ent[i] * 0.5f;
            gC[i * 2 + 0] = cosf(th);
            gC[i * 2 + 1] = sinf(th);
        }
        return;
    }
    int gi = blockIdx.x * 256 + threadIdx.x;
    int row = gi / NQ;
    int q   = gi - row * NQ;
    const float4* xr = (const float4*)(x + row * IN_SZ);
    const float4* wr = (const float4*)(w + q * IN_SZ);
    float acc = 0.f;
    for (int k = 0; k < IN_SZ / 4; k++) {
        float4 xv = xr[k];
        float4 wv = wr[k];
        acc += xv.x * wv.x + xv.y * wv.y + xv.z * wv.z + xv.w * wv.w;
    }
    enc[gi] = acc + bvec[q];
}

// ---------------- block-wide sum (result broadcast) ----------------
__device__ float blockAllSum(float v, float* scr) {
    #pragma unroll
    for (int o = 32; o > 0; o >>= 1) v += __shfl_down(v, o, 64);
    int lane = threadIdx.x & 63, w = threadIdx.x >> 6;
    __syncthreads();
    if (lane == 0) scr[w] = v;
    __syncthreads();
    return scr[0] + scr[1] + scr[2] + scr[3];
}

// ================= K2: batchnorm1 stats =================
__global__ void k_bnstats(const float* __restrict__ xm, float* __restrict__ mo,
                          float* __restrict__ ro, int ncols, int nrows) {
    __shared__ float scr[8];
    int j = blockIdx.x, t = threadIdx.x;
    float s = 0.f;
    for (int b = t; b < nrows; b += 256) s += xm[b * ncols + j];
    float mean = blockAllSum(s, scr) / (float)nrows;
    float s2 = 0.f;
    for (int b = t; b < nrows; b += 256) {
        float d = xm[b * ncols + j] - mean;
        s2 += d * d;
    }
    float var = blockAllSum(s2, scr) / (float)nrows;
    if (t == 0) {
        mo[j] = mean;
        ro[j] = 1.f / sqrtf(var + BN_EPS);
    }
}

// ================= K3: quantum circuit — windowed in-place LDS passes =================
// Canonical amp index: qubit q at bit (11-q). LDS slot swizzle: slot = idx ^ ((idx>>4)&15).
// Window A: local nibble = idx bits 3..0  (qubits 8..11); thread supplies bits 11..4 = T
// Window B: local nibble = idx bits 7..4  (qubits 4..7);  T[7:4]->bits 11..8, T[3:0]->bits 3..0
// Window C: local nibble = idx bits 11..8 (qubits 0..3);  T -> bits 7..0
//
// KEY: windows A and B partition LDS identically by idx bits 11..8 = T[7:4]; the 16
// threads sharing T[7:4] are 16 contiguous lanes inside ONE wave. DS ops from one wave
// complete in order, so A<->B transitions need NO __syncthreads — only B<->C does.
#define SLA(m) ((T << 4) | ((m) ^ (T & 15)))
#define SLB(m) (((T & 0xF0) << 4) | ((m) << 4) | ((T ^ (m)) & 15))
#define SLC(m) (((m) << 8) | (T & 0xF0) | ((T ^ (T >> 4)) & 15))

#define LOADW(SL) do {                                                          \
    s0=xch[SL(0)];  s1=xch[SL(1)];  s2=xch[SL(2)];  s3=xch[SL(3)];              \
    s4=xch[SL(4)];  s5=xch[SL(5)];  s6=xch[SL(6)];  s7=xch[SL(7)];              \
    s8=xch[SL(8)];  s9=xch[SL(9)];  s10=xch[SL(10)]; s11=xch[SL(11)];           \
    s12=xch[SL(12)]; s13=xch[SL(13)]; s14=xch[SL(14)]; s15=xch[SL(15)]; } while (0)
#define STORW(SL) do {                                                          \
    xch[SL(0)]=s0;  xch[SL(1)]=s1;  xch[SL(2)]=s2;  xch[SL(3)]=s3;              \
    xch[SL(4)]=s4;  xch[SL(5)]=s5;  xch[SL(6)]=s6;  xch[SL(7)]=s7;              \
    xch[SL(8)]=s8;  xch[SL(9)]=s9;  xch[SL(10)]=s10; xch[SL(11)]=s11;           \
    xch[SL(12)]=s12; xch[SL(13)]=s13; xch[SL(14)]=s14; xch[SL(15)]=s15; } while (0)

// complex 2x2 on pair (A,B) with coeffs u00..u11 in scope
#define U_PAIR(A, B) { float2 a0 = A, a1 = B;                                   \
    A.x = u00r*a0.x - u00i*a0.y + u01r*a1.x - u01i*a1.y;                        \
    A.y = u00r*a0.y + u00i*a0.x + u01r*a1.y + u01i*a1.x;                        \
    B.x = u10r*a0.x - u10i*a0.y + u11r*a1.x - u11i*a1.y;                        \
    B.y = u10r*a0.y + u10i*a0.x + u11r*a1.y + u11i*a1.x; }

#define U_LOAD(uptr) const float* u_ = (uptr);                                   \
    float u00r=u_[0], u00i=u_[1], u01r=u_[2], u01i=u_[3],                        \
          u10r=u_[4], u10i=u_[5], u11r=u_[6], u11i=u_[7];

#define APPLY_U_K3(uptr) do { U_LOAD(uptr)                                      \
    U_PAIR(s0,s8) U_PAIR(s1,s9) U_PAIR(s2,s10) U_PAIR(s3,s11)                   \
    U_PAIR(s4,s12) U_PAIR(s5,s13) U_PAIR(s6,s14) U_PAIR(s7,s15) } while (0)
#define APPLY_U_K2(uptr) do { U_LOAD(uptr)                                      \
    U_PAIR(s0,s4) U_PAIR(s1,s5) U_PAIR(s2,s6) U_PAIR(s3,s7)                     \
    U_PAIR(s8,s12) U_PAIR(s9,s13) U_PAIR(s10,s14) U_PAIR(s11,s15) } while (0)
#define APPLY_U_K1(uptr) do { U_LOAD(uptr)                                      \
    U_PAIR(s0,s2) U_PAIR(s1,s3) U_PAIR(s4,s6) U_PAIR(s5,s7)                     \
    U_PAIR(s8,s10) U_PAIR(s9,s11) U_PAIR(s12,s14) U_PAIR(s13,s15) } while (0)
#define APPLY_U_K0(uptr) do { U_LOAD(uptr)                                      \
    U_PAIR(s0,s1) U_PAIR(s2,s3) U_PAIR(s4,s5) U_PAIR(s6,s7)                     \
    U_PAIR(s8,s9) U_PAIR(s10,s11) U_PAIR(s12,s13) U_PAIR(s14,s15) } while (0)

#define RY_PAIR(A, B) { float2 a0 = A, a1 = B;                                  \
    A.x = c_*a0.x - sn_*a1.x;  A.y = c_*a0.y - sn_*a1.y;                        \
    B.x = sn_*a0.x + c_*a1.x;  B.y = sn_*a0.y + c_*a1.y; }

#define CRY_32(cc, ss) do { float c_=(cc), sn_=(ss);                            \
    RY_PAIR(s8,s12) RY_PAIR(s9,s13) RY_PAIR(s10,s14) RY_PAIR(s11,s15) } while (0)
#define CRY_21(cc, ss) do { float c_=(cc), sn_=(ss);                            \
    RY_PAIR(s4,s6) RY_PAIR(s5,s7) RY_PAIR(s12,s14) RY_PAIR(s13,s15) } while (0)
#define CRY_10(cc, ss) do { float c_=(cc), sn_=(ss);                            \
    RY_PAIR(s2,s3) RY_PAIR(s6,s7) RY_PAIR(s10,s11) RY_PAIR(s14,s15) } while (0)
#define RYALL_K3(cc, ss) do { float c_=(cc), sn_=(ss);                          \
    RY_PAIR(s0,s8) RY_PAIR(s1,s9) RY_PAIR(s2,s10) RY_PAIR(s3,s11)               \
    RY_PAIR(s4,s12) RY_PAIR(s5,s13) RY_PAIR(s6,s14) RY_PAIR(s7,s15) } while (0)

#define INITJ(j) make_float2(f * (((j)&8)?a81:a80) * (((j)&4)?a91:a90)          \
                               * (((j)&2)?aa1:aa0) * (((j)&1)?ab1:ab0), 0.f)
#define PRJ(S) ((S).x*(S).x + (S).y*(S).y)
#define WREDUCE(v) { v += __shfl_down(v,32,64); v += __shfl_down(v,16,64);      \
    v += __shfl_down(v,8,64); v += __shfl_down(v,4,64);                         \
    v += __shfl_down(v,2,64); v += __shfl_down(v,1,64); }

__launch_bounds__(256)
__global__ void k_quantum(const float* __restrict__ enc,
                          const float* __restrict__ bn1m, const float* __restrict__ bn1r,
                          const float* __restrict__ g1, const float* __restrict__ b1,
                          const float* __restrict__ gU, const float* __restrict__ gC,
                          float* __restrict__ probs) {
    __shared__ float2 xch[NST];                                  // 32 KB
    __shared__ float  gbuf[DEPTH * NQ * 8 + DEPTH * (NQ - 1) * 2];
    __shared__ float  qv[NQ][2];
    __shared__ float  hbuf[NQ];

    int T = threadIdx.x, b = blockIdx.x;

    for (int i = T; i < 354; i += 256) gbuf[i] = (i < 288) ? gU[i] : gC[i - 288];

    if (T < NQ) {
        float e = enc[b * NQ + T];
        hbuf[T] = tanhf(g1[T] * (e - bn1m[T]) * bn1r[T] + b1[T]);
    }
    __syncthreads();
    if (T < NQ) {
        float n2 = 0.f;
        #pragma unroll
        for (int i = 0; i < NQ; i++) n2 += hbuf[i] * hbuf[i];
        float norm = sqrtf(n2);
        float h = hbuf[T];
        float a = (norm > 0.f) ? h / fmaxf(norm, 1e-30f) : h;
        float amp = fminf(fabsf(a), 1.f);
        float ch  = sqrtf(fmaxf(1.f - amp * amp, 0.f));
        qv[T][0] = ch;
        qv[T][1] = (a < 0.f) ? -amp : amp;
    }
    __syncthreads();

    float2 s0, s1, s2, s3, s4, s5, s6, s7, s8, s9, s10, s11, s12, s13, s14, s15;

    // ---- init (window A order) + U on qubits 8..11 of layer 0, store ----
    {
        float f = 1.f;
        #pragma unroll
        for (int q = 0; q < 8; q++) f *= qv[q][(T >> (7 - q)) & 1];
        float a80 = qv[8][0],  a81 = qv[8][1];
        float a90 = qv[9][0],  a91 = qv[9][1];
        float aa0 = qv[10][0], aa1 = qv[10][1];
        float ab0 = qv[11][0], ab1 = qv[11][1];
        s0 = INITJ(0);  s1 = INITJ(1);  s2 = INITJ(2);  s3 = INITJ(3);
        s4 = INITJ(4);  s5 = INITJ(5);  s6 = INITJ(6);  s7 = INITJ(7);
        s8 = INITJ(8);  s9 = INITJ(9);  s10 = INITJ(10); s11 = INITJ(11);
        s12 = INITJ(12); s13 = INITJ(13); s14 = INITJ(14); s15 = INITJ(15);
        const float* U0 = gbuf;
        APPLY_U_K3(U0 + 8 * 8);
        APPLY_U_K2(U0 + 9 * 8);
        APPLY_U_K1(U0 + 10 * 8);
        APPLY_U_K0(U0 + 11 * 8);
        STORW(SLA);
        __builtin_amdgcn_wave_barrier();      // A->B is wave-private: no __syncthreads
    }

    #pragma unroll 1
    for (int l = 0; l < DEPTH; l++) {
        const float* UL = gbuf + l * 96;
        const float* CL = gbuf + 288 + l * 22;
        // ---- window B: U on qubits 4..7 ----
        LOADW(SLB);
        APPLY_U_K3(UL + 4 * 8);
        APPLY_U_K2(UL + 5 * 8);
        APPLY_U_K1(UL + 6 * 8);
        APPLY_U_K0(UL + 7 * 8);
        STORW(SLB);
        __syncthreads();                      // B->C crosses waves
        // ---- window C: U on qubits 0..3; CRY0..2 ----
        LOADW(SLC);
        APPLY_U_K3(UL + 0 * 8);
        APPLY_U_K2(UL + 1 * 8);
        APPLY_U_K1(UL + 2 * 8);
        APPLY_U_K0(UL + 3 * 8);
        CRY_32(CL[0], CL[1]);
        CRY_21(CL[2], CL[3]);
        CRY_10(CL[4], CL[5]);
        STORW(SLC);
        __syncthreads();                      // C->B crosses waves
        // ---- window B: CRY3 (control = idx bit 8 = T&16), CRY4..6 ----
        LOADW(SLB);
        if (T & 16) RYALL_K3(CL[6], CL[7]);
        CRY_32(CL[8], CL[9]);
        CRY_21(CL[10], CL[11]);
        CRY_10(CL[12], CL[13]);
        STORW(SLB);
        __builtin_amdgcn_wave_barrier();      // B->A is wave-private
        // ---- window A: CRY7 (control = idx bit 4 = T&1), CRY8..10 [+ next layer's U8..11] ----
        LOADW(SLA);
        if (T & 1) RYALL_K3(CL[14], CL[15]);
        CRY_32(CL[16], CL[17]);
        CRY_21(CL[18], CL[19]);
        CRY_10(CL[20], CL[21]);
        if (l < DEPTH - 1) {
            const float* UN = gbuf + (l + 1) * 96;
            APPLY_U_K3(UN + 8 * 8);
            APPLY_U_K2(UN + 9 * 8);
            APPLY_U_K1(UN + 10 * 8);
            APPLY_U_K0(UN + 11 * 8);
            STORW(SLA);
            __builtin_amdgcn_wave_barrier();  // A->B next iter is wave-private
        }
    }

    // ---- marginals from registers (window A: idx = T<<4 | m) ----
    float p0 = PRJ(s0),  p1 = PRJ(s1),  p2 = PRJ(s2),  p3 = PRJ(s3);
    float p4 = PRJ(s4),  p5 = PRJ(s5),  p6 = PRJ(s6),  p7 = PRJ(s7);
    float p8 = PRJ(s8),  p9 = PRJ(s9),  p10 = PRJ(s10), p11 = PRJ(s11);
    float p12 = PRJ(s12), p13 = PRJ(s13), p14 = PRJ(s14), p15 = PRJ(s15);
    float tot = p0+p1+p2+p3+p4+p5+p6+p7+p8+p9+p10+p11+p12+p13+p14+p15;
    float r8  = p8+p9+p10+p11+p12+p13+p14+p15;
    float r9  = p4+p5+p6+p7+p12+p13+p14+p15;
    float r10 = p2+p3+p6+p7+p10+p11+p14+p15;
    float r11 = p1+p3+p5+p7+p9+p11+p13+p15;
    float r0 = (T & 128) ? tot : 0.f;
    float r1 = (T & 64)  ? tot : 0.f;
    float r2 = (T & 32)  ? tot : 0.f;
    float r3 = (T & 16)  ? tot : 0.f;
    float r4 = (T & 8)   ? tot : 0.f;
    float r5 = (T & 4)   ? tot : 0.f;
    float r6 = (T & 2)   ? tot : 0.f;
    float r7 = (T & 1)   ? tot : 0.f;

    WREDUCE(r0) WREDUCE(r1) WREDUCE(r2) WREDUCE(r3) WREDUCE(r4) WREDUCE(r5)
    WREDUCE(r6) WREDUCE(r7) WREDUCE(r8) WREDUCE(r9) WREDUCE(r10) WREDUCE(r11)

    __syncthreads();                     // xch no longer needed as state
    float* red = (float*)xch;
    int lane = T & 63, w = T >> 6;
    if (lane == 0) {
        float* rr = red + w * NQ;
        rr[0]=r0; rr[1]=r1; rr[2]=r2; rr[3]=r3; rr[4]=r4; rr[5]=r5;
        rr[6]=r6; rr[7]=r7; rr[8]=r8; rr[9]=r9; rr[10]=r10; rr[11]=r11;
    }
    __syncthreads();
    if (T < NQ) probs[b * NQ + T] = red[T] + red[NQ + T] + red[2 * NQ + T] + red[3 * NQ + T];
}

// ================= K4: prob moments -> pmean + cov (one pass) =================
__global__ void k_pcov(const float* __restrict__ probs, float* __restrict__ pmean,
                       float* __restrict__ cov) {
    __shared__ float scr[8];
    int blk = blockIdx.x;             // 0..143
    int q = blk / NQ, q2 = blk % NQ;
    int t = threadIdx.x;
    float sx = 0.f, sy = 0.f, sxy = 0.f;
    for (int b = t; b < BATCH; b += 256) {
        float xv = probs[b * NQ + q];
        float yv = probs[b * NQ + q2];
        sx += xv; sy += yv; sxy += xv * yv;
    }
    float SX  = blockAllSum(sx,  scr);
    float SY  = blockAllSum(sy,  scr);
    float SXY = blockAllSum(sxy, scr);
    if (t == 0) {
        float mx = SX / (float)BATCH, my = SY / (float)BATCH;
        cov[blk] = SXY / (float)BATCH - mx * my;
        if (q == q2) pmean[q] = mx;
    }
}

// ================= K5: final decode + BN2 =================
__global__ void k_final(const float* __restrict__ probs, const float* __restrict__ pmean,
                        const float* __restrict__ cov, const float* __restrict__ dw,
                        const float* __restrict__ g2, const float* __restrict__ b2,
                        float* __restrict__ out) {
    __shared__ float cv[NQ * NQ];
    __shared__ float cp[NQ];
    int b = blockIdx.x, t = threadIdx.x;
    if (t < NQ * NQ) cv[t] = cov[t];
    if (t < NQ) cp[t] = probs[b * NQ + t] - pmean[t];
    __syncthreads();
    float w[NQ];
    #pragma unroll
    for (int q = 0; q < NQ; q++) w[q] = dw[t * NQ + q];
    float var = 0.f, acc = 0.f;
    #pragma unroll
    for (int q = 0; q < NQ; q++) {
        float a = 0.f;
        #pragma unroll
        for (int q2 = 0; q2 < NQ; q2++) a += cv[q * NQ + q2] * w[q2];
        var += w[q] * a;
        acc += cp[q] * w[q];
    }
    out[b * OUT_SZ + t] = acc * (1.f / sqrtf(var + BN_EPS)) * g2[t] + b2[t];
}

extern "C" void kernel_launch(void* const* d_in, const int* in_sizes, int n_in,
                              void* d_out, int out_size, void* d_ws, size_t ws_size,
                              hipStream_t stream) {
    const float* x     = (const float*)d_in[0];
    const float* enc_w = (const float*)d_in[1];
    const float* enc_b = (const float*)d_in[2];
    const float* rot   = (const float*)d_in[3];
    const float* ent   = (const float*)d_in[4];
    const float* dec_w = (const float*)d_in[5];
    // d_in[6] = dec_b — cancels inside BN2
    const float* g1    = (const float*)d_in[7];
    const float* b1    = (const float*)d_in[8];
    const float* g2    = (const float*)d_in[9];
    const float* b2    = (const float*)d_in[10];

    float* ws    = (float*)d_ws;
    float* enc   = ws + OFF_ENC;
    float* bn1m  = ws + OFF_BN1M;
    float* bn1r  = ws + OFF_BN1R;
    float* gU    = ws + OFF_GU;
    float* gC    = ws + OFF_GC;
    float* prb   = ws + OFF_PROBS;
    float* pmean = ws + OFF_PMEAN;
    float* cov   = ws + OFF_COV;

    hipLaunchKernelGGL(k_encode, dim3(193), dim3(256), 0, stream,
                       x, enc_w, enc_b, rot, ent, enc, gU, gC);
    hipLaunchKernelGGL(k_bnstats, dim3(NQ), dim3(256), 0, stream, enc, bn1m, bn1r, NQ, BATCH);
    hipLaunchKernelGGL(k_quantum, dim3(BATCH), dim3(256), 0, stream,
                       enc, bn1m, bn1r, g1, b1, gU, gC, prb);
    hipLaunchKernelGGL(k_pcov, dim3(NQ * NQ), dim3(256), 0, stream, prb, pmean, cov);
    hipLaunchKernelGGL(k_final, dim3(BATCH), dim3(OUT_SZ), 0, stream,
                       prb, pmean, cov, dec_w, g2, b2, (float*)d_out);
}

// Round 8
// 331.893 us; speedup vs baseline: 1.2574x; 1.0560x over previous
//
#include <hip/hip_runtime.h>

#define BATCH   4096
#define IN_SZ   512
#define NQ      12
#define OUT_SZ  256
#define DEPTH   3
#define NST     4096   // 2^NQ
#define BN_EPS  1e-5f

// ---- ws layout (in floats) ----
#define OFF_ENC    0            // 4096*12 = 49152
#define OFF_BN1M   49152
#define OFF_BN1R   49168
#define OFF_GU     49184        // 288
#define OFF_GC     49472        // 66 (pad 96)
#define OFF_PROBS  49568        // 49152
#define OFF_PMEAN  98720
#define OFF_COV    98736        // 144

// ================= K1: encode (+ fused gate precompute in block 192) =================
__global__ void k_encode(const float* __restrict__ x, const float* __restrict__ w,
                         const float* __restrict__ bvec,
                         const float* __restrict__ rot, const float* __restrict__ ent,
                         float* __restrict__ enc, float* __restrict__ gU, float* __restrict__ gC) {
    if (blockIdx.x == 192) {
        int t = threadIdx.x;
        if (t < DEPTH * NQ) {
            float ax = rot[t * 3 + 0] * 0.5f;
            float ay = rot[t * 3 + 1] * 0.5f;
            float az = rot[t * 3 + 2] * 0.5f;
            float cx = cosf(ax), sx = sinf(ax);
            float cy = cosf(ay), sy = sinf(ay);
            float cz = cosf(az), sz = sinf(az);
            float m00r =  cy * cx, m00i =  sy * sx;
            float m01r = -sy * cx, m01i = -cy * sx;
            float m10r =  sy * cx, m10i = -cy * sx;
            float m11r =  cy * cx, m11i = -sy * sx;
            float* o = gU + t * 8;
            o[0] = cz * m00r + sz * m00i;  o[1] = cz * m00i - sz * m00r;
            o[2] = cz * m01r + sz * m01i;  o[3] = cz * m01i - sz * m01r;
            o[4] = cz * m10r - sz * m10i;  o[5] = cz * m10i + sz * m10r;
            o[6] = cz * m11r - sz * m11i;  o[7] = cz * m11i + sz * m11r;
        }
        if (t >= 64 && t - 64 < DEPTH * (NQ - 1)) {
            int i = t - 64;
            float th = ent[i] * 0.5f;
            gC[i * 2 + 0] = cosf(th);
            gC[i * 2 + 1] = sinf(th);
        }
        return;
    }
    int gi = blockIdx.x * 256 + threadIdx.x;
    int row = gi / NQ;
    int q   = gi - row * NQ;
    const float4* xr = (const float4*)(x + row * IN_SZ);
    const float4* wr = (const float4*)(w + q * IN_SZ);
    float acc = 0.f;
    for (int k = 0; k < IN_SZ / 4; k++) {
        float4 xv = xr[k];
        float4 wv = wr[k];
        acc += xv.x * wv.x + xv.y * wv.y + xv.z * wv.z + xv.w * wv.w;
    }
    enc[gi] = acc + bvec[q];
}

// ---------------- block-wide sum (result broadcast) ----------------
__device__ float blockAllSum(float v, float* scr) {
    #pragma unroll
    for (int o = 32; o > 0; o >>= 1) v += __shfl_down(v, o, 64);
    int lane = threadIdx.x & 63, w = threadIdx.x >> 6;
    __syncthreads();
    if (lane == 0) scr[w] = v;
    __syncthreads();
    return scr[0] + scr[1] + scr[2] + scr[3];
}

// ================= K2: batchnorm1 stats =================
__global__ void k_bnstats(const float* __restrict__ xm, float* __restrict__ mo,
                          float* __restrict__ ro, int ncols, int nrows) {
    __shared__ float scr[8];
    int j = blockIdx.x, t = threadIdx.x;
    float s = 0.f;
    for (int b = t; b < nrows; b += 256) s += xm[b * ncols + j];
    float mean = blockAllSum(s, scr) / (float)nrows;
    float s2 = 0.f;
    for (int b = t; b < nrows; b += 256) {
        float d = xm[b * ncols + j] - mean;
        s2 += d * d;
    }
    float var = blockAllSum(s2, scr) / (float)nrows;
    if (t == 0) {
        mo[j] = mean;
        ro[j] = 1.f / sqrtf(var + BN_EPS);
    }
}

// ================= K3: quantum circuit — windowed in-place LDS passes =================
// Canonical amp index: qubit q at bit (11-q). LDS slot swizzle: slot = idx ^ ((idx>>4)&15).
// Window A: local nibble = idx bits 3..0  (qubits 8..11); thread supplies bits 11..4 = T
// Window B: local nibble = idx bits 7..4  (qubits 4..7)
// Window C: local nibble = idx bits 11..8 (qubits 0..3)
// A<->B transitions are wave-private (idx bits 11..8 = T[7:4], 16 contiguous lanes);
// only B<->C needs __syncthreads.
// Gate coefficients are wave-uniform -> read straight from GLOBAL memory (s_load /
// SGPR operands), freeing the DS pipe. Only xch lives in LDS (exactly 32 KB -> 5 blk/CU).
#define SLA(m) ((T << 4) | ((m) ^ (T & 15)))
#define SLB(m) (((T & 0xF0) << 4) | ((m) << 4) | ((T ^ (m)) & 15))
#define SLC(m) (((m) << 8) | (T & 0xF0) | ((T ^ (T >> 4)) & 15))

#define LOADW(SL) do {                                                          \
    s0=xch[SL(0)];  s1=xch[SL(1)];  s2=xch[SL(2)];  s3=xch[SL(3)];              \
    s4=xch[SL(4)];  s5=xch[SL(5)];  s6=xch[SL(6)];  s7=xch[SL(7)];              \
    s8=xch[SL(8)];  s9=xch[SL(9)];  s10=xch[SL(10)]; s11=xch[SL(11)];           \
    s12=xch[SL(12)]; s13=xch[SL(13)]; s14=xch[SL(14)]; s15=xch[SL(15)]; } while (0)
#define STORW(SL) do {                                                          \
    xch[SL(0)]=s0;  xch[SL(1)]=s1;  xch[SL(2)]=s2;  xch[SL(3)]=s3;              \
    xch[SL(4)]=s4;  xch[SL(5)]=s5;  xch[SL(6)]=s6;  xch[SL(7)]=s7;              \
    xch[SL(8)]=s8;  xch[SL(9)]=s9;  xch[SL(10)]=s10; xch[SL(11)]=s11;           \
    xch[SL(12)]=s12; xch[SL(13)]=s13; xch[SL(14)]=s14; xch[SL(15)]=s15; } while (0)

#define U_PAIR(A, B) { float2 a0 = A, a1 = B;                                   \
    A.x = u00r*a0.x - u00i*a0.y + u01r*a1.x - u01i*a1.y;                        \
    A.y = u00r*a0.y + u00i*a0.x + u01r*a1.y + u01i*a1.x;                        \
    B.x = u10r*a0.x - u10i*a0.y + u11r*a1.x - u11i*a1.y;                        \
    B.y = u10r*a0.y + u10i*a0.x + u11r*a1.y + u11i*a1.x; }

#define U_LOAD(uptr) const float* u_ = (uptr);                                   \
    float u00r=u_[0], u00i=u_[1], u01r=u_[2], u01i=u_[3],                        \
          u10r=u_[4], u10i=u_[5], u11r=u_[6], u11i=u_[7];

#define APPLY_U_K3(uptr) do { U_LOAD(uptr)                                      \
    U_PAIR(s0,s8) U_PAIR(s1,s9) U_PAIR(s2,s10) U_PAIR(s3,s11)                   \
    U_PAIR(s4,s12) U_PAIR(s5,s13) U_PAIR(s6,s14) U_PAIR(s7,s15) } while (0)
#define APPLY_U_K2(uptr) do { U_LOAD(uptr)                                      \
    U_PAIR(s0,s4) U_PAIR(s1,s5) U_PAIR(s2,s6) U_PAIR(s3,s7)                     \
    U_PAIR(s8,s12) U_PAIR(s9,s13) U_PAIR(s10,s14) U_PAIR(s11,s15) } while (0)
#define APPLY_U_K1(uptr) do { U_LOAD(uptr)                                      \
    U_PAIR(s0,s2) U_PAIR(s1,s3) U_PAIR(s4,s6) U_PAIR(s5,s7)                     \
    U_PAIR(s8,s10) U_PAIR(s9,s11) U_PAIR(s12,s14) U_PAIR(s13,s15) } while (0)
#define APPLY_U_K0(uptr) do { U_LOAD(uptr)                                      \
    U_PAIR(s0,s1) U_PAIR(s2,s3) U_PAIR(s4,s5) U_PAIR(s6,s7)                     \
    U_PAIR(s8,s9) U_PAIR(s10,s11) U_PAIR(s12,s13) U_PAIR(s14,s15) } while (0)

#define RY_PAIR(A, B) { float2 a0 = A, a1 = B;                                  \
    A.x = c_*a0.x - sn_*a1.x;  A.y = c_*a0.y - sn_*a1.y;                        \
    B.x = sn_*a0.x + c_*a1.x;  B.y = sn_*a0.y + c_*a1.y; }

#define CRY_32(cc, ss) do { float c_=(cc), sn_=(ss);                            \
    RY_PAIR(s8,s12) RY_PAIR(s9,s13) RY_PAIR(s10,s14) RY_PAIR(s11,s15) } while (0)
#define CRY_21(cc, ss) do { float c_=(cc), sn_=(ss);                            \
    RY_PAIR(s4,s6) RY_PAIR(s5,s7) RY_PAIR(s12,s14) RY_PAIR(s13,s15) } while (0)
#define CRY_10(cc, ss) do { float c_=(cc), sn_=(ss);                            \
    RY_PAIR(s2,s3) RY_PAIR(s6,s7) RY_PAIR(s10,s11) RY_PAIR(s14,s15) } while (0)
#define RYALL_K3(cc, ss) do { float c_=(cc), sn_=(ss);                          \
    RY_PAIR(s0,s8) RY_PAIR(s1,s9) RY_PAIR(s2,s10) RY_PAIR(s3,s11)               \
    RY_PAIR(s4,s12) RY_PAIR(s5,s13) RY_PAIR(s6,s14) RY_PAIR(s7,s15) } while (0)

#define INITJ(j) make_float2(f * (((j)&8)?qs8:qc8) * (((j)&4)?qs9:qc9)          \
                               * (((j)&2)?qs10:qc10) * (((j)&1)?qs11:qc11), 0.f)
#define PRJ(S) ((S).x*(S).x + (S).y*(S).y)
#define WREDUCE(v) { v += __shfl_down(v,32,64); v += __shfl_down(v,16,64);      \
    v += __shfl_down(v,8,64); v += __shfl_down(v,4,64);                         \
    v += __shfl_down(v,2,64); v += __shfl_down(v,1,64); }

// per-qubit amplitude pair (uniform in block, computed redundantly per thread)
#define MKQ(i) float qc##i, qs##i; {                                            \
    float h_ = h##i;                                                            \
    float a_ = nz ? h_ * rinv : h_;                                             \
    float amp_ = fminf(fabsf(a_), 1.f);                                         \
    qc##i = sqrtf(fmaxf(1.f - amp_ * amp_, 0.f));                               \
    qs##i = (a_ < 0.f) ? -amp_ : amp_; }

__launch_bounds__(256)
__global__ void k_quantum(const float* __restrict__ enc,
                          const float* __restrict__ bn1m, const float* __restrict__ bn1r,
                          const float* __restrict__ g1, const float* __restrict__ b1,
                          const float* __restrict__ gU, const float* __restrict__ gC,
                          float* __restrict__ probs) {
    __shared__ float2 xch[NST];                                  // exactly 32 KB

    int T = threadIdx.x, b = blockIdx.x;

    // ---- BN1 + tanh + qv, all uniform scalars computed in registers ----
    const float* er = enc + b * NQ;
    float h0  = tanhf(g1[0]  * (er[0]  - bn1m[0])  * bn1r[0]  + b1[0]);
    float h1  = tanhf(g1[1]  * (er[1]  - bn1m[1])  * bn1r[1]  + b1[1]);
    float h2  = tanhf(g1[2]  * (er[2]  - bn1m[2])  * bn1r[2]  + b1[2]);
    float h3  = tanhf(g1[3]  * (er[3]  - bn1m[3])  * bn1r[3]  + b1[3]);
    float h4  = tanhf(g1[4]  * (er[4]  - bn1m[4])  * bn1r[4]  + b1[4]);
    float h5  = tanhf(g1[5]  * (er[5]  - bn1m[5])  * bn1r[5]  + b1[5]);
    float h6  = tanhf(g1[6]  * (er[6]  - bn1m[6])  * bn1r[6]  + b1[6]);
    float h7  = tanhf(g1[7]  * (er[7]  - bn1m[7])  * bn1r[7]  + b1[7]);
    float h8  = tanhf(g1[8]  * (er[8]  - bn1m[8])  * bn1r[8]  + b1[8]);
    float h9  = tanhf(g1[9]  * (er[9]  - bn1m[9])  * bn1r[9]  + b1[9]);
    float h10 = tanhf(g1[10] * (er[10] - bn1m[10]) * bn1r[10] + b1[10]);
    float h11 = tanhf(g1[11] * (er[11] - bn1m[11]) * bn1r[11] + b1[11]);
    float n2 = h0*h0+h1*h1+h2*h2+h3*h3+h4*h4+h5*h5+h6*h6+h7*h7
             + h8*h8+h9*h9+h10*h10+h11*h11;
    float norm = sqrtf(n2);
    bool  nz   = norm > 0.f;
    float rinv = 1.f / fmaxf(norm, 1e-30f);
    MKQ(0) MKQ(1) MKQ(2) MKQ(3) MKQ(4) MKQ(5) MKQ(6) MKQ(7)
    MKQ(8) MKQ(9) MKQ(10) MKQ(11)

    float2 s0, s1, s2, s3, s4, s5, s6, s7, s8, s9, s10, s11, s12, s13, s14, s15;

    // ---- init (window A order): qubit q selected by T bit (7-q) for q<8 ----
    {
        float f = ((T>>7)&1 ? qs0 : qc0) * ((T>>6)&1 ? qs1 : qc1)
                * ((T>>5)&1 ? qs2 : qc2) * ((T>>4)&1 ? qs3 : qc3)
                * ((T>>3)&1 ? qs4 : qc4) * ((T>>2)&1 ? qs5 : qc5)
                * ((T>>1)&1 ? qs6 : qc6) * ((T>>0)&1 ? qs7 : qc7);
        s0 = INITJ(0);  s1 = INITJ(1);  s2 = INITJ(2);  s3 = INITJ(3);
        s4 = INITJ(4);  s5 = INITJ(5);  s6 = INITJ(6);  s7 = INITJ(7);
        s8 = INITJ(8);  s9 = INITJ(9);  s10 = INITJ(10); s11 = INITJ(11);
        s12 = INITJ(12); s13 = INITJ(13); s14 = INITJ(14); s15 = INITJ(15);
        APPLY_U_K3(gU + 8 * 8);
        APPLY_U_K2(gU + 9 * 8);
        APPLY_U_K1(gU + 10 * 8);
        APPLY_U_K0(gU + 11 * 8);
        STORW(SLA);
        __builtin_amdgcn_wave_barrier();      // A->B is wave-private
    }

    #pragma unroll 1
    for (int l = 0; l < DEPTH; l++) {
        const float* UL = gU + l * 96;
        const float* CL = gC + l * 22;
        // ---- window B: U on qubits 4..7 ----
        LOADW(SLB);
        APPLY_U_K3(UL + 4 * 8);
        APPLY_U_K2(UL + 5 * 8);
        APPLY_U_K1(UL + 6 * 8);
        APPLY_U_K0(UL + 7 * 8);
        STORW(SLB);
        __syncthreads();                      // B->C crosses waves
        // ---- window C: U on qubits 0..3; CRY0..2 ----
        LOADW(SLC);
        APPLY_U_K3(UL + 0 * 8);
        APPLY_U_K2(UL + 1 * 8);
        APPLY_U_K1(UL + 2 * 8);
        APPLY_U_K0(UL + 3 * 8);
        CRY_32(CL[0], CL[1]);
        CRY_21(CL[2], CL[3]);
        CRY_10(CL[4], CL[5]);
        STORW(SLC);
        __syncthreads();                      // C->B crosses waves
        // ---- window B: CRY3 (control = idx bit 8 = T&16), CRY4..6 ----
        LOADW(SLB);
        if (T & 16) RYALL_K3(CL[6], CL[7]);
        CRY_32(CL[8], CL[9]);
        CRY_21(CL[10], CL[11]);
        CRY_10(CL[12], CL[13]);
        STORW(SLB);
        __builtin_amdgcn_wave_barrier();      // B->A is wave-private
        // ---- window A: CRY7 (control = idx bit 4 = T&1), CRY8..10 [+ next U8..11] ----
        LOADW(SLA);
        if (T & 1) RYALL_K3(CL[14], CL[15]);
        CRY_32(CL[16], CL[17]);
        CRY_21(CL[18], CL[19]);
        CRY_10(CL[20], CL[21]);
        if (l < DEPTH - 1) {
            const float* UN = gU + (l + 1) * 96;
            APPLY_U_K3(UN + 8 * 8);
            APPLY_U_K2(UN + 9 * 8);
            APPLY_U_K1(UN + 10 * 8);
            APPLY_U_K0(UN + 11 * 8);
            STORW(SLA);
            __builtin_amdgcn_wave_barrier();  // A->B next iter is wave-private
        }
    }

    // ---- marginals from registers (window A: idx = T<<4 | m) ----
    float p0 = PRJ(s0),  p1 = PRJ(s1),  p2 = PRJ(s2),  p3 = PRJ(s3);
    float p4 = PRJ(s4),  p5 = PRJ(s5),  p6 = PRJ(s6),  p7 = PRJ(s7);
    float p8 = PRJ(s8),  p9 = PRJ(s9),  p10 = PRJ(s10), p11 = PRJ(s11);
    float p12 = PRJ(s12), p13 = PRJ(s13), p14 = PRJ(s14), p15 = PRJ(s15);
    float tot = p0+p1+p2+p3+p4+p5+p6+p7+p8+p9+p10+p11+p12+p13+p14+p15;
    float r8  = p8+p9+p10+p11+p12+p13+p14+p15;
    float r9  = p4+p5+p6+p7+p12+p13+p14+p15;
    float r10 = p2+p3+p6+p7+p10+p11+p14+p15;
    float r11 = p1+p3+p5+p7+p9+p11+p13+p15;
    float r0 = (T & 128) ? tot : 0.f;
    float r1 = (T & 64)  ? tot : 0.f;
    float r2 = (T & 32)  ? tot : 0.f;
    float r3 = (T & 16)  ? tot : 0.f;
    float r4 = (T & 8)   ? tot : 0.f;
    float r5 = (T & 4)   ? tot : 0.f;
    float r6 = (T & 2)   ? tot : 0.f;
    float r7 = (T & 1)   ? tot : 0.f;

    WREDUCE(r0) WREDUCE(r1) WREDUCE(r2) WREDUCE(r3) WREDUCE(r4) WREDUCE(r5)
    WREDUCE(r6) WREDUCE(r7) WREDUCE(r8) WREDUCE(r9) WREDUCE(r10) WREDUCE(r11)

    __syncthreads();                     // xch no longer needed as state
    float* red = (float*)xch;
    int lane = T & 63, w = T >> 6;
    if (lane == 0) {
        float* rr = red + w * NQ;
        rr[0]=r0; rr[1]=r1; rr[2]=r2; rr[3]=r3; rr[4]=r4; rr[5]=r5;
        rr[6]=r6; rr[7]=r7; rr[8]=r8; rr[9]=r9; rr[10]=r10; rr[11]=r11;
    }
    __syncthreads();
    if (T < NQ) probs[b * NQ + T] = red[T] + red[NQ + T] + red[2 * NQ + T] + red[3 * NQ + T];
}

// ================= K4: prob moments -> pmean + cov (one pass) =================
__global__ void k_pcov(const float* __restrict__ probs, float* __restrict__ pmean,
                       float* __restrict__ cov) {
    __shared__ float scr[8];
    int blk = blockIdx.x;             // 0..143
    int q = blk / NQ, q2 = blk % NQ;
    int t = threadIdx.x;
    float sx = 0.f, sy = 0.f, sxy = 0.f;
    for (int b = t; b < BATCH; b += 256) {
        float xv = probs[b * NQ + q];
        float yv = probs[b * NQ + q2];
        sx += xv; sy += yv; sxy += xv * yv;
    }
    float SX  = blockAllSum(sx,  scr);
    float SY  = blockAllSum(sy,  scr);
    float SXY = blockAllSum(sxy, scr);
    if (t == 0) {
        float mx = SX / (float)BATCH, my = SY / (float)BATCH;
        cov[blk] = SXY / (float)BATCH - mx * my;
        if (q == q2) pmean[q] = mx;
    }
}

// ================= K5: final decode + BN2 =================
__global__ void k_final(const float* __restrict__ probs, const float* __restrict__ pmean,
                        const float* __restrict__ cov, const float* __restrict__ dw,
                        const float* __restrict__ g2, const float* __restrict__ b2,
                        float* __restrict__ out) {
    __shared__ float cv[NQ * NQ];
    __shared__ float cp[NQ];
    int b = blockIdx.x, t = threadIdx.x;
    if (t < NQ * NQ) cv[t] = cov[t];
    if (t < NQ) cp[t] = probs[b * NQ + t] - pmean[t];
    __syncthreads();
    float w[NQ];
    #pragma unroll
    for (int q = 0; q < NQ; q++) w[q] = dw[t * NQ + q];
    float var = 0.f, acc = 0.f;
    #pragma unroll
    for (int q = 0; q < NQ; q++) {
        float a = 0.f;
        #pragma unroll
        for (int q2 = 0; q2 < NQ; q2++) a += cv[q * NQ + q2] * w[q2];
        var += w[q] * a;
        acc += cp[q] * w[q];
    }
    out[b * OUT_SZ + t] = acc * (1.f / sqrtf(var + BN_EPS)) * g2[t] + b2[t];
}

extern "C" void kernel_launch(void* const* d_in, const int* in_sizes, int n_in,
                              void* d_out, int out_size, void* d_ws, size_t ws_size,
                              hipStream_t stream) {
    const float* x     = (const float*)d_in[0];
    const float* enc_w = (const float*)d_in[1];
    const float* enc_b = (const float*)d_in[2];
    const float* rot   = (const float*)d_in[3];
    const float* ent   = (const float*)d_in[4];
    const float* dec_w = (const float*)d_in[5];
    // d_in[6] = dec_b — cancels inside BN2
    const float* g1    = (const float*)d_in[7];
    const float* b1    = (const float*)d_in[8];
    const float* g2    = (const float*)d_in[9];
    const float* b2    = (const float*)d_in[10];

    float* ws    = (float*)d_ws;
    float* enc   = ws + OFF_ENC;
    float* bn1m  = ws + OFF_BN1M;
    float* bn1r  = ws + OFF_BN1R;
    float* gU    = ws + OFF_GU;
    float* gC    = ws + OFF_GC;
    float* prb   = ws + OFF_PROBS;
    float* pmean = ws + OFF_PMEAN;
    float* cov   = ws + OFF_COV;

    hipLaunchKernelGGL(k_encode, dim3(193), dim3(256), 0, stream,
                       x, enc_w, enc_b, rot, ent, enc, gU, gC);
    hipLaunchKernelGGL(k_bnstats, dim3(NQ), dim3(256), 0, stream, enc, bn1m, bn1r, NQ, BATCH);
    hipLaunchKernelGGL(k_quantum, dim3(BATCH), dim3(256), 0, stream,
                       enc, bn1m, bn1r, g1, b1, gU, gC, prb);
    hipLaunchKernelGGL(k_pcov, dim3(NQ * NQ), dim3(256), 0, stream, prb, pmean, cov);
    hipLaunchKernelGGL(k_final, dim3(BATCH), dim3(OUT_SZ), 0, stream,
                       prb, pmean, cov, dec_w, g2, b2, (float*)d_out);
}

// Round 9
// 244.261 us; speedup vs baseline: 1.7086x; 1.3588x over previous
//
#include <hip/hip_runtime.h>

#define BATCH   4096
#define IN_SZ   512
#define NQ      12
#define OUT_SZ  256
#define DEPTH   3
#define NST     4096   // 2^NQ
#define BN_EPS  1e-5f

// ---- ws layout (in floats) ----
#define OFF_ENC    0            // 4096*12 = 49152
#define OFF_BN1M   49152
#define OFF_BN1R   49168
#define OFF_GU     49184        // 288
#define OFF_GC     49472        // 66 (pad 96)
#define OFF_PROBS  49568        // 49152
#define OFF_PMEAN  98720
#define OFF_COV    98736        // 144

typedef float v2f __attribute__((ext_vector_type(2)));
typedef float v4f __attribute__((ext_vector_type(4)));
#define SW2(a) __builtin_shufflevector(a, a, 1, 0)

// ================= K1: encode (+ fused gate precompute in block 192) =================
__global__ void k_encode(const float* __restrict__ x, const float* __restrict__ w,
                         const float* __restrict__ bvec,
                         const float* __restrict__ rot, const float* __restrict__ ent,
                         float* __restrict__ enc, float* __restrict__ gU, float* __restrict__ gC) {
    if (blockIdx.x == 192) {
        int t = threadIdx.x;
        if (t < DEPTH * NQ) {
            float ax = rot[t * 3 + 0] * 0.5f;
            float ay = rot[t * 3 + 1] * 0.5f;
            float az = rot[t * 3 + 2] * 0.5f;
            float cx = cosf(ax), sx = sinf(ax);
            float cy = cosf(ay), sy = sinf(ay);
            float cz = cosf(az), sz = sinf(az);
            float m00r =  cy * cx, m00i =  sy * sx;
            float m01r = -sy * cx, m01i = -cy * sx;
            float m10r =  sy * cx, m10i = -cy * sx;
            float m11r =  cy * cx, m11i = -sy * sx;
            float* o = gU + t * 8;
            o[0] = cz * m00r + sz * m00i;  o[1] = cz * m00i - sz * m00r;
            o[2] = cz * m01r + sz * m01i;  o[3] = cz * m01i - sz * m01r;
            o[4] = cz * m10r - sz * m10i;  o[5] = cz * m10i + sz * m10r;
            o[6] = cz * m11r - sz * m11i;  o[7] = cz * m11i + sz * m11r;
        }
        if (t >= 64 && t - 64 < DEPTH * (NQ - 1)) {
            int i = t - 64;
            float th = ent[i] * 0.5f;
            gC[i * 2 + 0] = cosf(th);
            gC[i * 2 + 1] = sinf(th);
        }
        return;
    }
    int gi = blockIdx.x * 256 + threadIdx.x;
    int row = gi / NQ;
    int q   = gi - row * NQ;
    const float4* xr = (const float4*)(x + row * IN_SZ);
    const float4* wr = (const float4*)(w + q * IN_SZ);
    float acc = 0.f;
    for (int k = 0; k < IN_SZ / 4; k++) {
        float4 xv = xr[k];
        float4 wv = wr[k];
        acc += xv.x * wv.x + xv.y * wv.y + xv.z * wv.z + xv.w * wv.w;
    }
    enc[gi] = acc + bvec[q];
}

// ---------------- block-wide sum (result broadcast) ----------------
__device__ float blockAllSum(float v, float* scr) {
    #pragma unroll
    for (int o = 32; o > 0; o >>= 1) v += __shfl_down(v, o, 64);
    int lane = threadIdx.x & 63, w = threadIdx.x >> 6;
    __syncthreads();
    if (lane == 0) scr[w] = v;
    __syncthreads();
    return scr[0] + scr[1] + scr[2] + scr[3];
}

// ================= K2: batchnorm1 stats =================
__global__ void k_bnstats(const float* __restrict__ xm, float* __restrict__ mo,
                          float* __restrict__ ro, int ncols, int nrows) {
    __shared__ float scr[8];
    int j = blockIdx.x, t = threadIdx.x;
    float s = 0.f;
    for (int b = t; b < nrows; b += 256) s += xm[b * ncols + j];
    float mean = blockAllSum(s, scr) / (float)nrows;
    float s2 = 0.f;
    for (int b = t; b < nrows; b += 256) {
        float d = xm[b * ncols + j] - mean;
        s2 += d * d;
    }
    float var = blockAllSum(s2, scr) / (float)nrows;
    if (t == 0) {
        mo[j] = mean;
        ro[j] = 1.f / sqrtf(var + BN_EPS);
    }
}

// ================= K3: quantum circuit — windowed LDS passes, packed-FP32 math =================
// Canonical amp index: qubit q at bit (11-q).
// Swizzle: slot = idx ^ (((idx>>5)&7)<<1)  — touches bits 3..1 only, so amp pairs
// (even,odd) stay adjacent -> window A uses ds_read/write_b128 (conflict-free:
// 8 lanes per disjoint 4-bank group). Windows B/C use b64 (2x factor, unchanged).
// Window A: local nibble = idx bits 3..0; thread supplies bits 11..4 = T
// Window B: local nibble = idx bits 7..4
// Window C: local nibble = idx bits 11..8
// A<->B transitions are wave-private (slot bits 11..8 = T[7:4], 16 contiguous lanes);
// only B<->C needs __syncthreads. Gate coeffs via wave-uniform global loads (SGPRs).
#define SLA2(j) ((T << 4) | ((((j) ^ ((T >> 1) & 7))) << 1))
#define SLB(m)  (((T & 0xF0) << 4) | ((m) << 4) | ((T & 15) ^ ((m) & 14)))
#define SLC(m)  (((m) << 8) | (T ^ ((((T >> 5) & 7)) << 1)))

#define LDA(j, Ra, Rb) { v4f t_ = *(const v4f*)(xch + SLA2(j));                 \
    Ra = __builtin_shufflevector(t_, t_, 0, 1);                                 \
    Rb = __builtin_shufflevector(t_, t_, 2, 3); }
#define STA(j, Ra, Rb) { v4f t_ = __builtin_shufflevector(Ra, Rb, 0, 1, 2, 3);  \
    *(v4f*)(xch + SLA2(j)) = t_; }

#define LOADA do { LDA(0,s0,s1) LDA(1,s2,s3) LDA(2,s4,s5) LDA(3,s6,s7)          \
    LDA(4,s8,s9) LDA(5,s10,s11) LDA(6,s12,s13) LDA(7,s14,s15) } while (0)
#define STORA do { STA(0,s0,s1) STA(1,s2,s3) STA(2,s4,s5) STA(3,s6,s7)          \
    STA(4,s8,s9) STA(5,s10,s11) STA(6,s12,s13) STA(7,s14,s15) } while (0)

#define LOADW(SL) do {                                                          \
    s0=xch[SL(0)];  s1=xch[SL(1)];  s2=xch[SL(2)];  s3=xch[SL(3)];              \
    s4=xch[SL(4)];  s5=xch[SL(5)];  s6=xch[SL(6)];  s7=xch[SL(7)];              \
    s8=xch[SL(8)];  s9=xch[SL(9)];  s10=xch[SL(10)]; s11=xch[SL(11)];           \
    s12=xch[SL(12)]; s13=xch[SL(13)]; s14=xch[SL(14)]; s15=xch[SL(15)]; } while (0)
#define STORW(SL) do {                                                          \
    xch[SL(0)]=s0;  xch[SL(1)]=s1;  xch[SL(2)]=s2;  xch[SL(3)]=s3;              \
    xch[SL(4)]=s4;  xch[SL(5)]=s5;  xch[SL(6)]=s6;  xch[SL(7)]=s7;              \
    xch[SL(8)]=s8;  xch[SL(9)]=s9;  xch[SL(10)]=s10; xch[SL(11)]=s11;           \
    xch[SL(12)]=s12; xch[SL(13)]=s13; xch[SL(14)]=s14; xch[SL(15)]=s15; } while (0)

// ---- packed complex 2x2: amp = (re,im) in one VGPR pair; complex mul =
// pk_mul + pk_fma with lane-swap (op_sel) and per-half neg ----
#define U_LOADP(uptr) const float* u_ = (uptr);                                  \
    v2f c00r = {u_[0], u_[0]}, c00i = {-u_[1], u_[1]};                           \
    v2f c01r = {u_[2], u_[2]}, c01i = {-u_[3], u_[3]};                           \
    v2f c10r = {u_[4], u_[4]}, c10i = {-u_[5], u_[5]};                           \
    v2f c11r = {u_[6], u_[6]}, c11i = {-u_[7], u_[7]};

#define U_PAIRP(A, B) { v2f a0 = A, a1 = B, a0s = SW2(a0), a1s = SW2(a1);        \
    A = a0*c00r + a0s*c00i + a1*c01r + a1s*c01i;                                 \
    B = a0*c10r + a0s*c10i + a1*c11r + a1s*c11i; }

#define APPLY_U_K3(uptr) do { U_LOADP(uptr)                                      \
    U_PAIRP(s0,s8) U_PAIRP(s1,s9) U_PAIRP(s2,s10) U_PAIRP(s3,s11)                \
    U_PAIRP(s4,s12) U_PAIRP(s5,s13) U_PAIRP(s6,s14) U_PAIRP(s7,s15) } while (0)
#define APPLY_U_K2(uptr) do { U_LOADP(uptr)                                      \
    U_PAIRP(s0,s4) U_PAIRP(s1,s5) U_PAIRP(s2,s6) U_PAIRP(s3,s7)                  \
    U_PAIRP(s8,s12) U_PAIRP(s9,s13) U_PAIRP(s10,s14) U_PAIRP(s11,s15) } while (0)
#define APPLY_U_K1(uptr) do { U_LOADP(uptr)                                      \
    U_PAIRP(s0,s2) U_PAIRP(s1,s3) U_PAIRP(s4,s6) U_PAIRP(s5,s7)                  \
    U_PAIRP(s8,s10) U_PAIRP(s9,s11) U_PAIRP(s12,s14) U_PAIRP(s13,s15) } while (0)
#define APPLY_U_K0(uptr) do { U_LOADP(uptr)                                      \
    U_PAIRP(s0,s1) U_PAIRP(s2,s3) U_PAIRP(s4,s5) U_PAIRP(s6,s7)                  \
    U_PAIRP(s8,s9) U_PAIRP(s10,s11) U_PAIRP(s12,s13) U_PAIRP(s14,s15) } while (0)

#define RY_PAIRP(A, B) { v2f a0 = A, a1 = B;                                     \
    A = a0*cc2 - a1*ss2;  B = a0*ss2 + a1*cc2; }

#define CRY_32(cc, ss) do { v2f cc2 = {(cc),(cc)}, ss2 = {(ss),(ss)};            \
    RY_PAIRP(s8,s12) RY_PAIRP(s9,s13) RY_PAIRP(s10,s14) RY_PAIRP(s11,s15) } while (0)
#define CRY_21(cc, ss) do { v2f cc2 = {(cc),(cc)}, ss2 = {(ss),(ss)};            \
    RY_PAIRP(s4,s6) RY_PAIRP(s5,s7) RY_PAIRP(s12,s14) RY_PAIRP(s13,s15) } while (0)
#define CRY_10(cc, ss) do { v2f cc2 = {(cc),(cc)}, ss2 = {(ss),(ss)};            \
    RY_PAIRP(s2,s3) RY_PAIRP(s6,s7) RY_PAIRP(s10,s11) RY_PAIRP(s14,s15) } while (0)
#define RYALL_K3(cc, ss) do { v2f cc2 = {(cc),(cc)}, ss2 = {(ss),(ss)};          \
    RY_PAIRP(s0,s8) RY_PAIRP(s1,s9) RY_PAIRP(s2,s10) RY_PAIRP(s3,s11)            \
    RY_PAIRP(s4,s12) RY_PAIRP(s5,s13) RY_PAIRP(s6,s14) RY_PAIRP(s7,s15) } while (0)

#define INITJ(SR, j) { SR.x = f * (((j)&8)?qs8:qc8) * (((j)&4)?qs9:qc9)          \
    * (((j)&2)?qs10:qc10) * (((j)&1)?qs11:qc11); SR.y = 0.f; }
#define PRJ(S) ((S).x*(S).x + (S).y*(S).y)
#define WREDUCE(v) { v += __shfl_down(v,32,64); v += __shfl_down(v,16,64);       \
    v += __shfl_down(v,8,64); v += __shfl_down(v,4,64);                          \
    v += __shfl_down(v,2,64); v += __shfl_down(v,1,64); }

// per-qubit amplitude pair (uniform in block, computed redundantly per thread)
#define MKQ(i) float qc##i, qs##i; {                                             \
    float h_ = h##i;                                                             \
    float a_ = nz ? h_ * rinv : h_;                                              \
    float amp_ = fminf(fabsf(a_), 1.f);                                          \
    qc##i = sqrtf(fmaxf(1.f - amp_ * amp_, 0.f));                                \
    qs##i = (a_ < 0.f) ? -amp_ : amp_; }

__launch_bounds__(256)
__global__ void k_quantum(const float* __restrict__ enc,
                          const float* __restrict__ bn1m, const float* __restrict__ bn1r,
                          const float* __restrict__ g1, const float* __restrict__ b1,
                          const float* __restrict__ gU, const float* __restrict__ gC,
                          float* __restrict__ probs) {
    __shared__ __align__(16) v2f xch[NST];                        // exactly 32 KB

    int T = threadIdx.x, b = blockIdx.x;

    // ---- BN1 + tanh + qv, all uniform scalars computed in registers ----
    const float* er = enc + b * NQ;
    float h0  = tanhf(g1[0]  * (er[0]  - bn1m[0])  * bn1r[0]  + b1[0]);
    float h1  = tanhf(g1[1]  * (er[1]  - bn1m[1])  * bn1r[1]  + b1[1]);
    float h2  = tanhf(g1[2]  * (er[2]  - bn1m[2])  * bn1r[2]  + b1[2]);
    float h3  = tanhf(g1[3]  * (er[3]  - bn1m[3])  * bn1r[3]  + b1[3]);
    float h4  = tanhf(g1[4]  * (er[4]  - bn1m[4])  * bn1r[4]  + b1[4]);
    float h5  = tanhf(g1[5]  * (er[5]  - bn1m[5])  * bn1r[5]  + b1[5]);
    float h6  = tanhf(g1[6]  * (er[6]  - bn1m[6])  * bn1r[6]  + b1[6]);
    float h7  = tanhf(g1[7]  * (er[7]  - bn1m[7])  * bn1r[7]  + b1[7]);
    float h8  = tanhf(g1[8]  * (er[8]  - bn1m[8])  * bn1r[8]  + b1[8]);
    float h9  = tanhf(g1[9]  * (er[9]  - bn1m[9])  * bn1r[9]  + b1[9]);
    float h10 = tanhf(g1[10] * (er[10] - bn1m[10]) * bn1r[10] + b1[10]);
    float h11 = tanhf(g1[11] * (er[11] - bn1m[11]) * bn1r[11] + b1[11]);
    float n2 = h0*h0+h1*h1+h2*h2+h3*h3+h4*h4+h5*h5+h6*h6+h7*h7
             + h8*h8+h9*h9+h10*h10+h11*h11;
    float norm = sqrtf(n2);
    bool  nz   = norm > 0.f;
    float rinv = 1.f / fmaxf(norm, 1e-30f);
    MKQ(0) MKQ(1) MKQ(2) MKQ(3) MKQ(4) MKQ(5) MKQ(6) MKQ(7)
    MKQ(8) MKQ(9) MKQ(10) MKQ(11)

    v2f s0, s1, s2, s3, s4, s5, s6, s7, s8, s9, s10, s11, s12, s13, s14, s15;

    // ---- init (window A order): qubit q selected by T bit (7-q) for q<8 ----
    {
        float f = ((T>>7)&1 ? qs0 : qc0) * ((T>>6)&1 ? qs1 : qc1)
                * ((T>>5)&1 ? qs2 : qc2) * ((T>>4)&1 ? qs3 : qc3)
                * ((T>>3)&1 ? qs4 : qc4) * ((T>>2)&1 ? qs5 : qc5)
                * ((T>>1)&1 ? qs6 : qc6) * ((T>>0)&1 ? qs7 : qc7);
        INITJ(s0,0)  INITJ(s1,1)  INITJ(s2,2)  INITJ(s3,3)
        INITJ(s4,4)  INITJ(s5,5)  INITJ(s6,6)  INITJ(s7,7)
        INITJ(s8,8)  INITJ(s9,9)  INITJ(s10,10) INITJ(s11,11)
        INITJ(s12,12) INITJ(s13,13) INITJ(s14,14) INITJ(s15,15)
        APPLY_U_K3(gU + 8 * 8);
        APPLY_U_K2(gU + 9 * 8);
        APPLY_U_K1(gU + 10 * 8);
        APPLY_U_K0(gU + 11 * 8);
        STORA;
        __builtin_amdgcn_wave_barrier();      // A->B is wave-private
    }

    #pragma unroll 1
    for (int l = 0; l < DEPTH; l++) {
        const float* UL = gU + l * 96;
        const float* CL = gC + l * 22;
        // ---- window B: U on qubits 4..7 ----
        LOADW(SLB);
        APPLY_U_K3(UL + 4 * 8);
        APPLY_U_K2(UL + 5 * 8);
        APPLY_U_K1(UL + 6 * 8);
        APPLY_U_K0(UL + 7 * 8);
        STORW(SLB);
        __syncthreads();                      // B->C crosses waves
        // ---- window C: U on qubits 0..3; CRY0..2 ----
        LOADW(SLC);
        APPLY_U_K3(UL + 0 * 8);
        APPLY_U_K2(UL + 1 * 8);
        APPLY_U_K1(UL + 2 * 8);
        APPLY_U_K0(UL + 3 * 8);
        CRY_32(CL[0], CL[1]);
        CRY_21(CL[2], CL[3]);
        CRY_10(CL[4], CL[5]);
        STORW(SLC);
        __syncthreads();                      // C->B crosses waves
        // ---- window B: CRY3 (control = idx bit 8 = T&16), CRY4..6 ----
        LOADW(SLB);
        if (T & 16) RYALL_K3(CL[6], CL[7]);
        CRY_32(CL[8], CL[9]);
        CRY_21(CL[10], CL[11]);
        CRY_10(CL[12], CL[13]);
        STORW(SLB);
        __builtin_amdgcn_wave_barrier();      // B->A is wave-private
        // ---- window A: CRY7 (control = idx bit 4 = T&1), CRY8..10 [+ next U8..11] ----
        LOADA;
        if (T & 1) RYALL_K3(CL[14], CL[15]);
        CRY_32(CL[16], CL[17]);
        CRY_21(CL[18], CL[19]);
        CRY_10(CL[20], CL[21]);
        if (l < DEPTH - 1) {
            const float* UN = gU + (l + 1) * 96;
            APPLY_U_K3(UN + 8 * 8);
            APPLY_U_K2(UN + 9 * 8);
            APPLY_U_K1(UN + 10 * 8);
            APPLY_U_K0(UN + 11 * 8);
            STORA;
            __builtin_amdgcn_wave_barrier();  // A->B next iter is wave-private
        }
    }

    // ---- marginals from registers (window A: idx = T<<4 | m) ----
    float p0 = PRJ(s0),  p1 = PRJ(s1),  p2 = PRJ(s2),  p3 = PRJ(s3);
    float p4 = PRJ(s4),  p5 = PRJ(s5),  p6 = PRJ(s6),  p7 = PRJ(s7);
    float p8 = PRJ(s8),  p9 = PRJ(s9),  p10 = PRJ(s10), p11 = PRJ(s11);
    float p12 = PRJ(s12), p13 = PRJ(s13), p14 = PRJ(s14), p15 = PRJ(s15);
    float tot = p0+p1+p2+p3+p4+p5+p6+p7+p8+p9+p10+p11+p12+p13+p14+p15;
    float r8  = p8+p9+p10+p11+p12+p13+p14+p15;
    float r9  = p4+p5+p6+p7+p12+p13+p14+p15;
    float r10 = p2+p3+p6+p7+p10+p11+p14+p15;
    float r11 = p1+p3+p5+p7+p9+p11+p13+p15;
    float r0 = (T & 128) ? tot : 0.f;
    float r1 = (T & 64)  ? tot : 0.f;
    float r2 = (T & 32)  ? tot : 0.f;
    float r3 = (T & 16)  ? tot : 0.f;
    float r4 = (T & 8)   ? tot : 0.f;
    float r5 = (T & 4)   ? tot : 0.f;
    float r6 = (T & 2)   ? tot : 0.f;
    float r7 = (T & 1)   ? tot : 0.f;

    WREDUCE(r0) WREDUCE(r1) WREDUCE(r2) WREDUCE(r3) WREDUCE(r4) WREDUCE(r5)
    WREDUCE(r6) WREDUCE(r7) WREDUCE(r8) WREDUCE(r9) WREDUCE(r10) WREDUCE(r11)

    __syncthreads();                     // xch no longer needed as state
    float* red = (float*)xch;
    int lane = T & 63, w = T >> 6;
    if (lane == 0) {
        float* rr = red + w * NQ;
        rr[0]=r0; rr[1]=r1; rr[2]=r2; rr[3]=r3; rr[4]=r4; rr[5]=r5;
        rr[6]=r6; rr[7]=r7; rr[8]=r8; rr[9]=r9; rr[10]=r10; rr[11]=r11;
    }
    __syncthreads();
    if (T < NQ) probs[b * NQ + T] = red[T] + red[NQ + T] + red[2 * NQ + T] + red[3 * NQ + T];
}

// ================= K4: prob moments -> pmean + cov (one pass) =================
__global__ void k_pcov(const float* __restrict__ probs, float* __restrict__ pmean,
                       float* __restrict__ cov) {
    __shared__ float scr[8];
    int blk = blockIdx.x;             // 0..143
    int q = blk / NQ, q2 = blk % NQ;
    int t = threadIdx.x;
    float sx = 0.f, sy = 0.f, sxy = 0.f;
    for (int b = t; b < BATCH; b += 256) {
        float xv = probs[b * NQ + q];
        float yv = probs[b * NQ + q2];
        sx += xv; sy += yv; sxy += xv * yv;
    }
    float SX  = blockAllSum(sx,  scr);
    float SY  = blockAllSum(sy,  scr);
    float SXY = blockAllSum(sxy, scr);
    if (t == 0) {
        float mx = SX / (float)BATCH, my = SY / (float)BATCH;
        cov[blk] = SXY / (float)BATCH - mx * my;
        if (q == q2) pmean[q] = mx;
    }
}

// ================= K5: final decode + BN2 =================
__global__ void k_final(const float* __restrict__ probs, const float* __restrict__ pmean,
                        const float* __restrict__ cov, const float* __restrict__ dw,
                        const float* __restrict__ g2, const float* __restrict__ b2,
                        float* __restrict__ out) {
    __shared__ float cv[NQ * NQ];
    __shared__ float cp[NQ];
    int b = blockIdx.x, t = threadIdx.x;
    if (t < NQ * NQ) cv[t] = cov[t];
    if (t < NQ) cp[t] = probs[b * NQ + t] - pmean[t];
    __syncthreads();
    float w[NQ];
    #pragma unroll
    for (int q = 0; q < NQ; q++) w[q] = dw[t * NQ + q];
    float var = 0.f, acc = 0.f;
    #pragma unroll
    for (int q = 0; q < NQ; q++) {
        float a = 0.f;
        #pragma unroll
        for (int q2 = 0; q2 < NQ; q2++) a += cv[q * NQ + q2] * w[q2];
        var += w[q] * a;
        acc += cp[q] * w[q];
    }
    out[b * OUT_SZ + t] = acc * (1.f / sqrtf(var + BN_EPS)) * g2[t] + b2[t];
}

extern "C" void kernel_launch(void* const* d_in, const int* in_sizes, int n_in,
                              void* d_out, int out_size, void* d_ws, size_t ws_size,
                              hipStream_t stream) {
    const float* x     = (const float*)d_in[0];
    const float* enc_w = (const float*)d_in[1];
    const float* enc_b = (const float*)d_in[2];
    const float* rot   = (const float*)d_in[3];
    const float* ent   = (const float*)d_in[4];
    const float* dec_w = (const float*)d_in[5];
    // d_in[6] = dec_b — cancels inside BN2
    const float* g1    = (const float*)d_in[7];
    const float* b1    = (const float*)d_in[8];
    const float* g2    = (const float*)d_in[9];
    const float* b2    = (const float*)d_in[10];

    float* ws    = (float*)d_ws;
    float* enc   = ws + OFF_ENC;
    float* bn1m  = ws + OFF_BN1M;
    float* bn1r  = ws + OFF_BN1R;
    float* gU    = ws + OFF_GU;
    float* gC    = ws + OFF_GC;
    float* prb   = ws + OFF_PROBS;
    float* pmean = ws + OFF_PMEAN;
    float* cov   = ws + OFF_COV;

    hipLaunchKernelGGL(k_encode, dim3(193), dim3(256), 0, stream,
                       x, enc_w, enc_b, rot, ent, enc, gU, gC);
    hipLaunchKernelGGL(k_bnstats, dim3(NQ), dim3(256), 0, stream, enc, bn1m, bn1r, NQ, BATCH);
    hipLaunchKernelGGL(k_quantum, dim3(BATCH), dim3(256), 0, stream,
                       enc, bn1m, bn1r, g1, b1, gU, gC, prb);
    hipLaunchKernelGGL(k_pcov, dim3(NQ * NQ), dim3(256), 0, stream, prb, pmean, cov);
    hipLaunchKernelGGL(k_final, dim3(BATCH), dim3(OUT_SZ), 0, stream,
                       prb, pmean, cov, dec_w, g2, b2, (float*)d_out);
}

// Round 10
// 219.090 us; speedup vs baseline: 1.9049x; 1.1149x over previous
//
#include <hip/hip_runtime.h>

#define BATCH   4096
#define IN_SZ   512
#define NQ      12
#define OUT_SZ  256
#define DEPTH   3
#define NST     4096   // 2^NQ
#define BN_EPS  1e-5f

// ---- ws layout (in floats) ----
#define OFF_ENC    0            // 4096*12 = 49152
#define OFF_BN1M   49152
#define OFF_BN1R   49168
#define OFF_GU     49184        // 288
#define OFF_GC     49472        // 66 (pad 96)
#define OFF_PROBS  49568        // 49152
#define OFF_PMEAN  98720
#define OFF_COV    98736        // 144
#define OFF_RSTD   98880        // 256

typedef float v2f __attribute__((ext_vector_type(2)));
typedef float v4f __attribute__((ext_vector_type(4)));
#define SW2(a) __builtin_shufflevector(a, a, 1, 0)

// ================= K1: encode, wave-per-row (+ gates in block 1024) =================
__global__ void k_encode(const float* __restrict__ x, const float* __restrict__ w,
                         const float* __restrict__ bvec,
                         const float* __restrict__ rot, const float* __restrict__ ent,
                         float* __restrict__ enc, float* __restrict__ gU, float* __restrict__ gC) {
    if (blockIdx.x == 1024) {
        int t = threadIdx.x;
        if (t < DEPTH * NQ) {
            float ax = rot[t * 3 + 0] * 0.5f;
            float ay = rot[t * 3 + 1] * 0.5f;
            float az = rot[t * 3 + 2] * 0.5f;
            float cx = cosf(ax), sx = sinf(ax);
            float cy = cosf(ay), sy = sinf(ay);
            float cz = cosf(az), sz = sinf(az);
            float m00r =  cy * cx, m00i =  sy * sx;
            float m01r = -sy * cx, m01i = -cy * sx;
            float m10r =  sy * cx, m10i = -cy * sx;
            float m11r =  cy * cx, m11i = -sy * sx;
            float* o = gU + t * 8;
            o[0] = cz * m00r + sz * m00i;  o[1] = cz * m00i - sz * m00r;
            o[2] = cz * m01r + sz * m01i;  o[3] = cz * m01i - sz * m01r;
            o[4] = cz * m10r - sz * m10i;  o[5] = cz * m10i + sz * m10r;
            o[6] = cz * m11r - sz * m11i;  o[7] = cz * m11i + sz * m11r;
        }
        if (t >= 64 && t - 64 < DEPTH * (NQ - 1)) {
            int i = t - 64;
            float th = ent[i] * 0.5f;
            gC[i * 2 + 0] = cosf(th);
            gC[i * 2 + 1] = sinf(th);
        }
        return;
    }
    int t = threadIdx.x;
    int wv = t >> 6, lane = t & 63;
    int row = blockIdx.x * 4 + wv;              // 1024 blocks x 4 waves = 4096 rows
    const float4* xr = (const float4*)(x + row * IN_SZ) + lane * 2;
    float4 xa = xr[0], xb = xr[1];
    float acc[NQ];
    #pragma unroll
    for (int q = 0; q < NQ; q++) {
        const float4* wr = (const float4*)(w + q * IN_SZ) + lane * 2;
        float4 wa = wr[0], wb = wr[1];
        float d = xa.x*wa.x + xa.y*wa.y + xa.z*wa.z + xa.w*wa.w
                + xb.x*wb.x + xb.y*wb.y + xb.z*wb.z + xb.w*wb.w;
        #pragma unroll
        for (int o = 32; o > 0; o >>= 1) d += __shfl_down(d, o, 64);
        acc[q] = d;
    }
    if (lane == 0) {
        float* er = enc + row * NQ;
        #pragma unroll
        for (int q = 0; q < NQ; q++) er[q] = acc[q] + bvec[q];
    }
}

// ---------------- block-wide sum for 256-thread blocks (broadcast) ----------------
__device__ float blockAllSum(float v, float* scr) {
    #pragma unroll
    for (int o = 32; o > 0; o >>= 1) v += __shfl_down(v, o, 64);
    int lane = threadIdx.x & 63, w = threadIdx.x >> 6;
    __syncthreads();
    if (lane == 0) scr[w] = v;
    __syncthreads();
    return scr[0] + scr[1] + scr[2] + scr[3];
}

// ================= K2: batchnorm1 stats — single pass, 1024 threads =================
__global__ void k_bnstats(const float* __restrict__ xm, float* __restrict__ mo,
                          float* __restrict__ ro) {
    __shared__ float scr[32];
    int j = blockIdx.x, t = threadIdx.x;
    float s = 0.f, s2 = 0.f;
    for (int b = t; b < BATCH; b += 1024) {
        float v = xm[b * NQ + j];
        s += v; s2 += v * v;
    }
    #pragma unroll
    for (int o = 32; o > 0; o >>= 1) { s += __shfl_down(s, o, 64); s2 += __shfl_down(s2, o, 64); }
    int lane = t & 63, w = t >> 6;
    if (lane == 0) { scr[w] = s; scr[16 + w] = s2; }
    __syncthreads();
    if (t == 0) {
        float S = 0.f, S2 = 0.f;
        #pragma unroll
        for (int i = 0; i < 16; i++) { S += scr[i]; S2 += scr[16 + i]; }
        float mean = S / (float)BATCH;
        float var  = S2 / (float)BATCH - mean * mean;
        mo[j] = mean;
        ro[j] = 1.f / sqrtf(var + BN_EPS);
    }
}

// ================= K3: quantum circuit — windowed LDS passes, packed-FP32 math =================
// Canonical amp index: qubit q at bit (11-q). Swizzle: slot = idx ^ (((idx>>5)&7)<<1)
// (bits 3..1 only -> amp pairs stay adjacent; window A uses b128).
// Window A: local nibble = idx bits 3..0; Window B: bits 7..4; Window C: bits 11..8.
// A<->B transitions are wave-private; only B<->C needs __syncthreads.
// Gate coeffs via wave-uniform global loads (SGPRs). Window offsets hoisted into
// VGPRs once (amdgpu_waves_per_eu(5,5) -> 102-reg budget; LDS caps at 5 blk/CU anyway).
#define SLA2(j) ((T << 4) | ((((j) ^ ((T >> 1) & 7))) << 1))
#define SLB(m)  (((T & 0xF0) << 4) | ((m) << 4) | ((T & 15) ^ ((m) & 14)))
#define SLC(m)  (((m) << 8) | (T ^ ((((T >> 5) & 7)) << 1)))

#define LDAo(o, Ra, Rb) { v4f t_ = *(const v4f*)(xch + (o));                    \
    Ra = __builtin_shufflevector(t_, t_, 0, 1);                                 \
    Rb = __builtin_shufflevector(t_, t_, 2, 3); }
#define STAo(o, Ra, Rb) { v4f t_ = __builtin_shufflevector(Ra, Rb, 0, 1, 2, 3); \
    *(v4f*)(xch + (o)) = t_; }

#define LOADA do { LDAo(oA0,s0,s1) LDAo(oA1,s2,s3) LDAo(oA2,s4,s5) LDAo(oA3,s6,s7) \
    LDAo(oA4,s8,s9) LDAo(oA5,s10,s11) LDAo(oA6,s12,s13) LDAo(oA7,s14,s15) } while (0)
#define STORA do { STAo(oA0,s0,s1) STAo(oA1,s2,s3) STAo(oA2,s4,s5) STAo(oA3,s6,s7) \
    STAo(oA4,s8,s9) STAo(oA5,s10,s11) STAo(oA6,s12,s13) STAo(oA7,s14,s15) } while (0)

#define LOADB do {                                                              \
    s0=xch[oB0];  s1=xch[oB1];  s2=xch[oB2];  s3=xch[oB3];                      \
    s4=xch[oB4];  s5=xch[oB5];  s6=xch[oB6];  s7=xch[oB7];                      \
    s8=xch[oB8];  s9=xch[oB9];  s10=xch[oB10]; s11=xch[oB11];                   \
    s12=xch[oB12]; s13=xch[oB13]; s14=xch[oB14]; s15=xch[oB15]; } while (0)
#define STORB do {                                                              \
    xch[oB0]=s0;  xch[oB1]=s1;  xch[oB2]=s2;  xch[oB3]=s3;                      \
    xch[oB4]=s4;  xch[oB5]=s5;  xch[oB6]=s6;  xch[oB7]=s7;                      \
    xch[oB8]=s8;  xch[oB9]=s9;  xch[oB10]=s10; xch[oB11]=s11;                   \
    xch[oB12]=s12; xch[oB13]=s13; xch[oB14]=s14; xch[oB15]=s15; } while (0)
#define LOADC do {                                                              \
    s0=xch[oC0];  s1=xch[oC1];  s2=xch[oC2];  s3=xch[oC3];                      \
    s4=xch[oC4];  s5=xch[oC5];  s6=xch[oC6];  s7=xch[oC7];                      \
    s8=xch[oC8];  s9=xch[oC9];  s10=xch[oC10]; s11=xch[oC11];                   \
    s12=xch[oC12]; s13=xch[oC13]; s14=xch[oC14]; s15=xch[oC15]; } while (0)
#define STORC do {                                                              \
    xch[oC0]=s0;  xch[oC1]=s1;  xch[oC2]=s2;  xch[oC3]=s3;                      \
    xch[oC4]=s4;  xch[oC5]=s5;  xch[oC6]=s6;  xch[oC7]=s7;                      \
    xch[oC8]=s8;  xch[oC9]=s9;  xch[oC10]=s10; xch[oC11]=s11;                   \
    xch[oC12]=s12; xch[oC13]=s13; xch[oC14]=s14; xch[oC15]=s15; } while (0)

#define U_LOADP(uptr) const float* u_ = (uptr);                                  \
    v2f c00r = {u_[0], u_[0]}, c00i = {-u_[1], u_[1]};                           \
    v2f c01r = {u_[2], u_[2]}, c01i = {-u_[3], u_[3]};                           \
    v2f c10r = {u_[4], u_[4]}, c10i = {-u_[5], u_[5]};                           \
    v2f c11r = {u_[6], u_[6]}, c11i = {-u_[7], u_[7]};

#define U_PAIRP(A, B) { v2f a0 = A, a1 = B, a0s = SW2(a0), a1s = SW2(a1);        \
    A = a0*c00r + a0s*c00i + a1*c01r + a1s*c01i;                                 \
    B = a0*c10r + a0s*c10i + a1*c11r + a1s*c11i; }

#define APPLY_U_K3(uptr) do { U_LOADP(uptr)                                      \
    U_PAIRP(s0,s8) U_PAIRP(s1,s9) U_PAIRP(s2,s10) U_PAIRP(s3,s11)                \
    U_PAIRP(s4,s12) U_PAIRP(s5,s13) U_PAIRP(s6,s14) U_PAIRP(s7,s15) } while (0)
#define APPLY_U_K2(uptr) do { U_LOADP(uptr)                                      \
    U_PAIRP(s0,s4) U_PAIRP(s1,s5) U_PAIRP(s2,s6) U_PAIRP(s3,s7)                  \
    U_PAIRP(s8,s12) U_PAIRP(s9,s13) U_PAIRP(s10,s14) U_PAIRP(s11,s15) } while (0)
#define APPLY_U_K1(uptr) do { U_LOADP(uptr)                                      \
    U_PAIRP(s0,s2) U_PAIRP(s1,s3) U_PAIRP(s4,s6) U_PAIRP(s5,s7)                  \
    U_PAIRP(s8,s10) U_PAIRP(s9,s11) U_PAIRP(s12,s14) U_PAIRP(s13,s15) } while (0)
#define APPLY_U_K0(uptr) do { U_LOADP(uptr)                                      \
    U_PAIRP(s0,s1) U_PAIRP(s2,s3) U_PAIRP(s4,s5) U_PAIRP(s6,s7)                  \
    U_PAIRP(s8,s9) U_PAIRP(s10,s11) U_PAIRP(s12,s13) U_PAIRP(s14,s15) } while (0)

#define RY_PAIRP(A, B) { v2f a0 = A, a1 = B;                                     \
    A = a0*cc2 - a1*ss2;  B = a0*ss2 + a1*cc2; }

#define CRY_32(cc, ss) do { v2f cc2 = {(cc),(cc)}, ss2 = {(ss),(ss)};            \
    RY_PAIRP(s8,s12) RY_PAIRP(s9,s13) RY_PAIRP(s10,s14) RY_PAIRP(s11,s15) } while (0)
#define CRY_21(cc, ss) do { v2f cc2 = {(cc),(cc)}, ss2 = {(ss),(ss)};            \
    RY_PAIRP(s4,s6) RY_PAIRP(s5,s7) RY_PAIRP(s12,s14) RY_PAIRP(s13,s15) } while (0)
#define CRY_10(cc, ss) do { v2f cc2 = {(cc),(cc)}, ss2 = {(ss),(ss)};            \
    RY_PAIRP(s2,s3) RY_PAIRP(s6,s7) RY_PAIRP(s10,s11) RY_PAIRP(s14,s15) } while (0)
#define RYALL_K3(cc, ss) do { v2f cc2 = {(cc),(cc)}, ss2 = {(ss),(ss)};          \
    RY_PAIRP(s0,s8) RY_PAIRP(s1,s9) RY_PAIRP(s2,s10) RY_PAIRP(s3,s11)            \
    RY_PAIRP(s4,s12) RY_PAIRP(s5,s13) RY_PAIRP(s6,s14) RY_PAIRP(s7,s15) } while (0)

#define INITJ(SR, j) { SR.x = f * (((j)&8)?qs8:qc8) * (((j)&4)?qs9:qc9)          \
    * (((j)&2)?qs10:qc10) * (((j)&1)?qs11:qc11); SR.y = 0.f; }
#define PRJ(S) ((S).x*(S).x + (S).y*(S).y)
#define WREDUCE(v) { v += __shfl_down(v,32,64); v += __shfl_down(v,16,64);       \
    v += __shfl_down(v,8,64); v += __shfl_down(v,4,64);                          \
    v += __shfl_down(v,2,64); v += __shfl_down(v,1,64); }

#define MKQ(i) float qc##i, qs##i; {                                             \
    float h_ = h##i;                                                             \
    float a_ = nz ? h_ * rinv : h_;                                              \
    float amp_ = fminf(fabsf(a_), 1.f);                                          \
    qc##i = sqrtf(fmaxf(1.f - amp_ * amp_, 0.f));                                \
    qs##i = (a_ < 0.f) ? -amp_ : amp_; }

__attribute__((amdgpu_waves_per_eu(5, 5)))
__global__ void __launch_bounds__(256)
k_quantum(const float* __restrict__ enc,
          const float* __restrict__ bn1m, const float* __restrict__ bn1r,
          const float* __restrict__ g1, const float* __restrict__ b1,
          const float* __restrict__ gU, const float* __restrict__ gC,
          float* __restrict__ probs) {
    __shared__ __align__(16) v2f xch[NST];                        // exactly 32 KB

    int T = threadIdx.x, b = blockIdx.x;

    // ---- hoisted window offsets (loop-invariant, live in VGPRs) ----
    const int oA0=SLA2(0), oA1=SLA2(1), oA2=SLA2(2), oA3=SLA2(3);
    const int oA4=SLA2(4), oA5=SLA2(5), oA6=SLA2(6), oA7=SLA2(7);
    const int oB0=SLB(0),  oB1=SLB(1),  oB2=SLB(2),  oB3=SLB(3);
    const int oB4=SLB(4),  oB5=SLB(5),  oB6=SLB(6),  oB7=SLB(7);
    const int oB8=SLB(8),  oB9=SLB(9),  oB10=SLB(10), oB11=SLB(11);
    const int oB12=SLB(12), oB13=SLB(13), oB14=SLB(14), oB15=SLB(15);
    const int oC0=SLC(0),  oC1=SLC(1),  oC2=SLC(2),  oC3=SLC(3);
    const int oC4=SLC(4),  oC5=SLC(5),  oC6=SLC(6),  oC7=SLC(7);
    const int oC8=SLC(8),  oC9=SLC(9),  oC10=SLC(10), oC11=SLC(11);
    const int oC12=SLC(12), oC13=SLC(13), oC14=SLC(14), oC15=SLC(15);

    // ---- BN1 + tanh + qv, all uniform scalars ----
    const float* er = enc + b * NQ;
    float h0  = tanhf(g1[0]  * (er[0]  - bn1m[0])  * bn1r[0]  + b1[0]);
    float h1  = tanhf(g1[1]  * (er[1]  - bn1m[1])  * bn1r[1]  + b1[1]);
    float h2  = tanhf(g1[2]  * (er[2]  - bn1m[2])  * bn1r[2]  + b1[2]);
    float h3  = tanhf(g1[3]  * (er[3]  - bn1m[3])  * bn1r[3]  + b1[3]);
    float h4  = tanhf(g1[4]  * (er[4]  - bn1m[4])  * bn1r[4]  + b1[4]);
    float h5  = tanhf(g1[5]  * (er[5]  - bn1m[5])  * bn1r[5]  + b1[5]);
    float h6  = tanhf(g1[6]  * (er[6]  - bn1m[6])  * bn1r[6]  + b1[6]);
    float h7  = tanhf(g1[7]  * (er[7]  - bn1m[7])  * bn1r[7]  + b1[7]);
    float h8  = tanhf(g1[8]  * (er[8]  - bn1m[8])  * bn1r[8]  + b1[8]);
    float h9  = tanhf(g1[9]  * (er[9]  - bn1m[9])  * bn1r[9]  + b1[9]);
    float h10 = tanhf(g1[10] * (er[10] - bn1m[10]) * bn1r[10] + b1[10]);
    float h11 = tanhf(g1[11] * (er[11] - bn1m[11]) * bn1r[11] + b1[11]);
    float n2 = h0*h0+h1*h1+h2*h2+h3*h3+h4*h4+h5*h5+h6*h6+h7*h7
             + h8*h8+h9*h9+h10*h10+h11*h11;
    float norm = sqrtf(n2);
    bool  nz   = norm > 0.f;
    float rinv = 1.f / fmaxf(norm, 1e-30f);
    MKQ(0) MKQ(1) MKQ(2) MKQ(3) MKQ(4) MKQ(5) MKQ(6) MKQ(7)
    MKQ(8) MKQ(9) MKQ(10) MKQ(11)

    v2f s0, s1, s2, s3, s4, s5, s6, s7, s8, s9, s10, s11, s12, s13, s14, s15;

    // ---- init (window A order) + U on qubits 8..11 of layer 0 ----
    {
        float f = ((T>>7)&1 ? qs0 : qc0) * ((T>>6)&1 ? qs1 : qc1)
                * ((T>>5)&1 ? qs2 : qc2) * ((T>>4)&1 ? qs3 : qc3)
                * ((T>>3)&1 ? qs4 : qc4) * ((T>>2)&1 ? qs5 : qc5)
                * ((T>>1)&1 ? qs6 : qc6) * ((T>>0)&1 ? qs7 : qc7);
        INITJ(s0,0)  INITJ(s1,1)  INITJ(s2,2)  INITJ(s3,3)
        INITJ(s4,4)  INITJ(s5,5)  INITJ(s6,6)  INITJ(s7,7)
        INITJ(s8,8)  INITJ(s9,9)  INITJ(s10,10) INITJ(s11,11)
        INITJ(s12,12) INITJ(s13,13) INITJ(s14,14) INITJ(s15,15)
        APPLY_U_K3(gU + 8 * 8);
        APPLY_U_K2(gU + 9 * 8);
        APPLY_U_K1(gU + 10 * 8);
        APPLY_U_K0(gU + 11 * 8);
        STORA;
        __builtin_amdgcn_wave_barrier();      // A->B is wave-private
    }

    #pragma unroll 1
    for (int l = 0; l < DEPTH; l++) {
        const float* UL = gU + l * 96;
        const float* CL = gC + l * 22;
        // ---- window B: U on qubits 4..7 ----
        LOADB;
        APPLY_U_K3(UL + 4 * 8);
        APPLY_U_K2(UL + 5 * 8);
        APPLY_U_K1(UL + 6 * 8);
        APPLY_U_K0(UL + 7 * 8);
        STORB;
        __syncthreads();                      // B->C crosses waves
        // ---- window C: U on qubits 0..3; CRY0..2 ----
        LOADC;
        APPLY_U_K3(UL + 0 * 8);
        APPLY_U_K2(UL + 1 * 8);
        APPLY_U_K1(UL + 2 * 8);
        APPLY_U_K0(UL + 3 * 8);
        CRY_32(CL[0], CL[1]);
        CRY_21(CL[2], CL[3]);
        CRY_10(CL[4], CL[5]);
        STORC;
        __syncthreads();                      // C->B crosses waves
        // ---- window B: CRY3 (control = idx bit 8 = T&16), CRY4..6 ----
        LOADB;
        if (T & 16) RYALL_K3(CL[6], CL[7]);
        CRY_32(CL[8], CL[9]);
        CRY_21(CL[10], CL[11]);
        CRY_10(CL[12], CL[13]);
        STORB;
        __builtin_amdgcn_wave_barrier();      // B->A is wave-private
        // ---- window A: CRY7 (control = idx bit 4 = T&1), CRY8..10 [+ next U8..11] ----
        LOADA;
        if (T & 1) RYALL_K3(CL[14], CL[15]);
        CRY_32(CL[16], CL[17]);
        CRY_21(CL[18], CL[19]);
        CRY_10(CL[20], CL[21]);
        if (l < DEPTH - 1) {
            const float* UN = gU + (l + 1) * 96;
            APPLY_U_K3(UN + 8 * 8);
            APPLY_U_K2(UN + 9 * 8);
            APPLY_U_K1(UN + 10 * 8);
            APPLY_U_K0(UN + 11 * 8);
            STORA;
            __builtin_amdgcn_wave_barrier();  // A->B next iter is wave-private
        }
    }

    // ---- marginals from registers (window A: idx = T<<4 | m) ----
    float p0 = PRJ(s0),  p1 = PRJ(s1),  p2 = PRJ(s2),  p3 = PRJ(s3);
    float p4 = PRJ(s4),  p5 = PRJ(s5),  p6 = PRJ(s6),  p7 = PRJ(s7);
    float p8 = PRJ(s8),  p9 = PRJ(s9),  p10 = PRJ(s10), p11 = PRJ(s11);
    float p12 = PRJ(s12), p13 = PRJ(s13), p14 = PRJ(s14), p15 = PRJ(s15);
    float tot = p0+p1+p2+p3+p4+p5+p6+p7+p8+p9+p10+p11+p12+p13+p14+p15;
    float r8  = p8+p9+p10+p11+p12+p13+p14+p15;
    float r9  = p4+p5+p6+p7+p12+p13+p14+p15;
    float r10 = p2+p3+p6+p7+p10+p11+p14+p15;
    float r11 = p1+p3+p5+p7+p9+p11+p13+p15;
    float r0 = (T & 128) ? tot : 0.f;
    float r1 = (T & 64)  ? tot : 0.f;
    float r2 = (T & 32)  ? tot : 0.f;
    float r3 = (T & 16)  ? tot : 0.f;
    float r4 = (T & 8)   ? tot : 0.f;
    float r5 = (T & 4)   ? tot : 0.f;
    float r6 = (T & 2)   ? tot : 0.f;
    float r7 = (T & 1)   ? tot : 0.f;

    WREDUCE(r0) WREDUCE(r1) WREDUCE(r2) WREDUCE(r3) WREDUCE(r4) WREDUCE(r5)
    WREDUCE(r6) WREDUCE(r7) WREDUCE(r8) WREDUCE(r9) WREDUCE(r10) WREDUCE(r11)

    __syncthreads();                     // xch no longer needed as state
    float* red = (float*)xch;
    int lane = T & 63, w = T >> 6;
    if (lane == 0) {
        float* rr = red + w * NQ;
        rr[0]=r0; rr[1]=r1; rr[2]=r2; rr[3]=r3; rr[4]=r4; rr[5]=r5;
        rr[6]=r6; rr[7]=r7; rr[8]=r8; rr[9]=r9; rr[10]=r10; rr[11]=r11;
    }
    __syncthreads();
    if (T < NQ) probs[b * NQ + T] = red[T] + red[NQ + T] + red[2 * NQ + T] + red[3 * NQ + T];
}

// ================= K4: prob moments -> pmean + cov (one pass) =================
__global__ void k_pcov(const float* __restrict__ probs, float* __restrict__ pmean,
                       float* __restrict__ cov) {
    __shared__ float scr[8];
    int blk = blockIdx.x;             // 0..143
    int q = blk / NQ, q2 = blk % NQ;
    int t = threadIdx.x;
    float sx = 0.f, sy = 0.f, sxy = 0.f;
    for (int b = t; b < BATCH; b += 256) {
        float xv = probs[b * NQ + q];
        float yv = probs[b * NQ + q2];
        sx += xv; sy += yv; sxy += xv * yv;
    }
    float SX  = blockAllSum(sx,  scr);
    float SY  = blockAllSum(sy,  scr);
    float SXY = blockAllSum(sxy, scr);
    if (t == 0) {
        float mx = SX / (float)BATCH, my = SY / (float)BATCH;
        cov[blk] = SXY / (float)BATCH - mx * my;
        if (q == q2) pmean[q] = mx;
    }
}

// ================= K5: rstd per output feature (1 block) =================
__global__ void k_rstd(const float* __restrict__ cov, const float* __restrict__ dw,
                       float* __restrict__ rstd) {
    __shared__ float cv[NQ * NQ];
    int t = threadIdx.x;
    if (t < NQ * NQ) cv[t] = cov[t];
    __syncthreads();
    float w[NQ];
    #pragma unroll
    for (int q = 0; q < NQ; q++) w[q] = dw[t * NQ + q];
    float var = 0.f;
    #pragma unroll
    for (int q = 0; q < NQ; q++) {
        float a = 0.f;
        #pragma unroll
        for (int q2 = 0; q2 < NQ; q2++) a += cv[q * NQ + q2] * w[q2];
        var += w[q] * a;
    }
    rstd[t] = 1.f / sqrtf(var + BN_EPS);
}

// ================= K6: final decode + BN2 (2 rows per block) =================
__global__ void k_final(const float* __restrict__ probs, const float* __restrict__ pmean,
                        const float* __restrict__ rstd, const float* __restrict__ dw,
                        const float* __restrict__ g2, const float* __restrict__ b2,
                        float* __restrict__ out) {
    __shared__ float cp[2][NQ];
    int b0 = blockIdx.x * 2;
    int t = threadIdx.x;
    int half = t >> 8, j = t & 255;
    if (t < NQ)                      cp[0][t]       = probs[b0 * NQ + t]        - pmean[t];
    else if (t >= 256 && t < 256+NQ) cp[1][t - 256] = probs[(b0+1) * NQ + t-256] - pmean[t - 256];
    __syncthreads();
    float acc = 0.f;
    #pragma unroll
    for (int q = 0; q < NQ; q++) acc += cp[half][q] * dw[j * NQ + q];
    out[(b0 + half) * OUT_SZ + j] = acc * rstd[j] * g2[j] + b2[j];
}

extern "C" void kernel_launch(void* const* d_in, const int* in_sizes, int n_in,
                              void* d_out, int out_size, void* d_ws, size_t ws_size,
                              hipStream_t stream) {
    const float* x     = (const float*)d_in[0];
    const float* enc_w = (const float*)d_in[1];
    const float* enc_b = (const float*)d_in[2];
    const float* rot   = (const float*)d_in[3];
    const float* ent   = (const float*)d_in[4];
    const float* dec_w = (const float*)d_in[5];
    // d_in[6] = dec_b — cancels inside BN2
    const float* g1    = (const float*)d_in[7];
    const float* b1    = (const float*)d_in[8];
    const float* g2    = (const float*)d_in[9];
    const float* b2    = (const float*)d_in[10];

    float* ws    = (float*)d_ws;
    float* enc   = ws + OFF_ENC;
    float* bn1m  = ws + OFF_BN1M;
    float* bn1r  = ws + OFF_BN1R;
    float* gU    = ws + OFF_GU;
    float* gC    = ws + OFF_GC;
    float* prb   = ws + OFF_PROBS;
    float* pmean = ws + OFF_PMEAN;
    float* cov   = ws + OFF_COV;
    float* rstd  = ws + OFF_RSTD;

    hipLaunchKernelGGL(k_encode, dim3(1025), dim3(256), 0, stream,
                       x, enc_w, enc_b, rot, ent, enc, gU, gC);
    hipLaunchKernelGGL(k_bnstats, dim3(NQ), dim3(1024), 0, stream, enc, bn1m, bn1r);
    hipLaunchKernelGGL(k_quantum, dim3(BATCH), dim3(256), 0, stream,
                       enc, bn1m, bn1r, g1, b1, gU, gC, prb);
    hipLaunchKernelGGL(k_pcov, dim3(NQ * NQ), dim3(256), 0, stream, prb, pmean, cov);
    hipLaunchKernelGGL(k_rstd, dim3(1), dim3(OUT_SZ), 0, stream, cov, dec_w, rstd);
    hipLaunchKernelGGL(k_final, dim3(BATCH / 2), dim3(512), 0, stream,
                       prb, pmean, rstd, dec_w, g2, b2, (float*)d_out);
}